// Round 1
// baseline (6833.733 us; speedup 1.0000x reference)
//
#include <hip/hip_runtime.h>
#include <math.h>

#define DEV static __device__ __forceinline__

DEV float gelu_exact(float x) {
    return 0.5f * x * (1.0f + erff(x * 0.70710678118654752f));
}

// ---------------- conv1: (B,1,512,200) -> (B,8,512,25), k=15 stride=8 pad=7 ----------------
__global__ void conv1_kernel(const float* __restrict__ x, const float* __restrict__ w,
                             const float* __restrict__ bias, float* __restrict__ out) {
    int idx = blockIdx.x * blockDim.x + threadIdx.x;
    const int total = 8 * 8 * 512 * 25;
    if (idx >= total) return;
    int ow = idx % 25;
    int p  = (idx / 25) % 512;
    int oc = (idx / (25 * 512)) % 8;
    int b  = idx / (25 * 512 * 8);
    const float* xp = x + b * 512 * 200 + p * 200;
    const float* wp = w + oc * 15;
    float acc = bias[oc];
    int t0 = ow * 8 - 7;
#pragma unroll
    for (int k = 0; k < 15; k++) {
        int t = t0 + k;
        if (t >= 0 && t < 200) acc += wp[k] * xp[t];
    }
    out[idx] = acc;
}

// ---------------- conv 1x3 (pad 1) on (B,8,512,25) ----------------
__global__ void conv3x1_kernel(const float* __restrict__ in, const float* __restrict__ w,
                               const float* __restrict__ bias, float* __restrict__ out) {
    int idx = blockIdx.x * blockDim.x + threadIdx.x;
    const int total = 8 * 8 * 512 * 25;
    if (idx >= total) return;
    int ow = idx % 25;
    int p  = (idx / 25) % 512;
    int oc = (idx / 12800) & 7;
    int b  = idx / 102400;
    float acc = bias[oc];
#pragma unroll
    for (int ic = 0; ic < 8; ic++) {
        const float* ip = in + b * 102400 + ic * 12800 + p * 25;
        const float* wp = w + oc * 24 + ic * 3;
        if (ow > 0)  acc += wp[0] * ip[ow - 1];
        acc += wp[1] * ip[ow];
        if (ow < 24) acc += wp[2] * ip[ow + 1];
    }
    out[idx] = acc;
}

// ---------------- groupnorm stats: one block per (b, group) ----------------
__global__ void gn_stats_kernel(const float* __restrict__ buf, float* __restrict__ stats) {
    int b = blockIdx.x >> 2, g = blockIdx.x & 3;
    const float* base = buf + b * 102400 + g * 2 * 12800;
    float s = 0.f, s2 = 0.f;
    for (int l = threadIdx.x; l < 25600; l += 256) {
        float v = base[l];
        s += v; s2 += v * v;
    }
    __shared__ float ss[256], ss2[256];
    ss[threadIdx.x] = s; ss2[threadIdx.x] = s2;
    __syncthreads();
    for (int o = 128; o; o >>= 1) {
        if (threadIdx.x < o) { ss[threadIdx.x] += ss[threadIdx.x + o]; ss2[threadIdx.x] += ss2[threadIdx.x + o]; }
        __syncthreads();
    }
    if (threadIdx.x == 0) {
        float m = ss[0] / 25600.f;
        float v = ss2[0] / 25600.f - m * m;
        stats[blockIdx.x * 2] = m;
        stats[blockIdx.x * 2 + 1] = v;
    }
}

__global__ void gn_apply_kernel(float* __restrict__ buf, const float* __restrict__ stats,
                                const float* __restrict__ g, const float* __restrict__ bb) {
    int idx = blockIdx.x * blockDim.x + threadIdx.x;
    if (idx >= 8 * 102400) return;
    int c = (idx / 12800) & 7;
    int b = idx / 102400;
    int grp = c >> 1;
    float m = stats[(b * 4 + grp) * 2];
    float v = stats[(b * 4 + grp) * 2 + 1];
    float val = (buf[idx] - m) * rsqrtf(v + 1e-5f) * g[c] + bb[c];
    buf[idx] = gelu_exact(val);
}

// ---------------- embed: conv(B,8,512,25) -> h(B,513,200) + cls + pos + time ----------------
__global__ void embed_kernel(const float* __restrict__ conv, const float* __restrict__ cls,
                             const float* __restrict__ pos, const float* __restrict__ te,
                             float* __restrict__ h) {
    int idx = blockIdx.x * blockDim.x + threadIdx.x;
    if (idx >= 8 * 513 * 200) return;
    int d = idx % 200;
    int n = (idx / 200) % 513;
    int b = idx / (200 * 513);
    float val;
    if (n == 0) {
        val = cls[d] + pos[d];
    } else {
        int p = n - 1;
        int t = d >> 3;   // 0..24  (feature = t*8 + c)
        int c = d & 7;
        val = conv[b * 102400 + c * 12800 + p * 25 + t];
        int ch = p >> 3, tw = p & 7;
        val += pos[(1 + ch) * 200 + d] + te[tw * 200 + d];
    }
    h[idx] = val;
}

// ---------------- LayerNorm over D=200, one wave per row ----------------
__global__ __launch_bounds__(64) void ln_kernel(const float* __restrict__ in,
                                                const float* __restrict__ g,
                                                const float* __restrict__ b,
                                                float* __restrict__ out) {
    int row = blockIdx.x;
    int lane = threadIdx.x;
    const float* x = in + row * 200;
    float v[4];
    float s = 0.f;
#pragma unroll
    for (int i = 0; i < 4; i++) {
        int d = lane + i * 64;
        v[i] = (d < 200) ? x[d] : 0.f;
        s += v[i];
    }
#pragma unroll
    for (int o = 32; o; o >>= 1) s += __shfl_xor(s, o);
    float mean = s * (1.f / 200.f);
    float s2 = 0.f;
#pragma unroll
    for (int i = 0; i < 4; i++) {
        int d = lane + i * 64;
        float dv = (d < 200) ? (v[i] - mean) : 0.f;
        s2 += dv * dv;
    }
#pragma unroll
    for (int o = 32; o; o >>= 1) s2 += __shfl_xor(s2, o);
    float rstd = rsqrtf(s2 * (1.f / 200.f) + 1e-6f);
#pragma unroll
    for (int i = 0; i < 4; i++) {
        int d = lane + i * 64;
        if (d < 200) out[row * 200 + d] = (v[i] - mean) * rstd * g[d] + b[d];
    }
}

// ---------------- tiled GEMM: C[M,N] = A[M,K] @ W[N,K]^T  (+ epilogue) ----------------
// EPI 0: C = acc
// EPI 1: C = res + gamma[n] * (acc + bias[n])
// EPI 2: C = gelu(acc + bias[n])
template <int EPI>
__global__ __launch_bounds__(256) void gemm_nt(const float* __restrict__ A,
                                               const float* __restrict__ W,
                                               float* __restrict__ C,
                                               const float* __restrict__ res,
                                               const float* __restrict__ bias,
                                               const float* __restrict__ gamma,
                                               int M, int N, int K) {
    __shared__ float As[16][65];
    __shared__ float Ws[16][65];
    int tx = threadIdx.x & 15, ty = threadIdx.x >> 4;
    int bm = blockIdx.y * 64, bn = blockIdx.x * 64;
    float acc[4][4] = {};
    for (int k0 = 0; k0 < K; k0 += 16) {
        for (int l = threadIdx.x; l < 64 * 16; l += 256) {
            int m = l >> 4, k = l & 15;
            int gk = k0 + k;
            int gm = bm + m;
            int gn = bn + m;
            As[k][m] = (gm < M && gk < K) ? A[gm * K + gk] : 0.f;
            Ws[k][m] = (gn < N && gk < K) ? W[gn * K + gk] : 0.f;
        }
        __syncthreads();
#pragma unroll
        for (int k = 0; k < 16; k++) {
            float a[4], w[4];
#pragma unroll
            for (int i = 0; i < 4; i++) a[i] = As[k][ty * 4 + i];
#pragma unroll
            for (int j = 0; j < 4; j++) w[j] = Ws[k][tx * 4 + j];
#pragma unroll
            for (int i = 0; i < 4; i++)
#pragma unroll
                for (int j = 0; j < 4; j++) acc[i][j] += a[i] * w[j];
        }
        __syncthreads();
    }
#pragma unroll
    for (int i = 0; i < 4; i++) {
        int gm = bm + ty * 4 + i;
        if (gm >= M) continue;
#pragma unroll
        for (int j = 0; j < 4; j++) {
            int gn = bn + tx * 4 + j;
            if (gn >= N) continue;
            float v = acc[i][j];
            if (EPI == 0) {
                C[gm * N + gn] = v;
            } else if (EPI == 1) {
                C[gm * N + gn] = res[gm * N + gn] + gamma[gn] * (v + bias[gn]);
            } else {
                C[gm * N + gn] = gelu_exact(v + bias[gn]);
            }
        }
    }
}

// ---------------- attention: one wave per (b, head, query) ----------------
__global__ __launch_bounds__(64) void attn_kernel(const float* __restrict__ qkv,
                                                  const float* __restrict__ table,
                                                  const int* __restrict__ ridx,
                                                  float* __restrict__ ob) {
    int bid = blockIdx.x;
    int n = bid % 513;
    int hh = (bid / 513) % 10;
    int b = bid / 5130;
    int lane = threadIdx.x;
    const float scale = 0.22360679774997896f; // 1/sqrt(20)
    const float* qp = qkv + (b * 513 + n) * 600 + hh * 20;
    float q[20];
#pragma unroll
    for (int i = 0; i < 20; i++) q[i] = qp[i] * scale;

    float sreg[9];
    float ml = -1e30f;
#pragma unroll
    for (int it = 0; it < 9; it++) {
        int m = lane + it * 64;
        float s = -1e30f;
        if (m < 513) {
            const float* kp = qkv + (b * 513 + m) * 600 + 200 + hh * 20;
            s = table[ridx[n * 513 + m] * 10 + hh];
#pragma unroll
            for (int i = 0; i < 20; i++) s += q[i] * kp[i];
        }
        sreg[it] = s;
        ml = fmaxf(ml, s);
    }
#pragma unroll
    for (int o = 32; o; o >>= 1) ml = fmaxf(ml, __shfl_xor(ml, o));

    float sum = 0.f;
    float acc[20] = {};
#pragma unroll
    for (int it = 0; it < 9; it++) {
        int m = lane + it * 64;
        if (m < 513) {
            float p = expf(sreg[it] - ml);
            sum += p;
            const float* vp = qkv + (b * 513 + m) * 600 + 400 + hh * 20;
#pragma unroll
            for (int i = 0; i < 20; i++) acc[i] += p * vp[i];
        }
    }
#pragma unroll
    for (int o = 32; o; o >>= 1) {
        sum += __shfl_xor(sum, o);
#pragma unroll
        for (int i = 0; i < 20; i++) acc[i] += __shfl_xor(acc[i], o);
    }
    if (lane == 0) {
        float inv = 1.f / sum;
        float* op = ob + (b * 513 + n) * 200 + hh * 20;
#pragma unroll
        for (int i = 0; i < 20; i++) op[i] = acc[i] * inv;
    }
}

// ---------------- final: mean-pool patches -> LN -> head (200 -> 4) ----------------
__global__ __launch_bounds__(256) void final_kernel(const float* __restrict__ h,
                                                    const float* __restrict__ g,
                                                    const float* __restrict__ bb,
                                                    const float* __restrict__ hw,
                                                    const float* __restrict__ hb,
                                                    float* __restrict__ out) {
    __shared__ float pool[256];
    __shared__ float red[256];
    int b = blockIdx.x, t = threadIdx.x;
    float s = 0.f;
    if (t < 200) {
        const float* hp = h + b * 513 * 200 + 200 + t;
        for (int p = 0; p < 512; p++) s += hp[p * 200];
        s *= (1.f / 512.f);
    }
    pool[t] = (t < 200) ? s : 0.f;
    red[t] = pool[t];
    __syncthreads();
    for (int o = 128; o; o >>= 1) {
        if (t < o) red[t] += red[t + o];
        __syncthreads();
    }
    float mean = red[0] / 200.f;
    __syncthreads();
    float dv = (t < 200) ? (pool[t] - mean) : 0.f;
    red[t] = dv * dv;
    __syncthreads();
    for (int o = 128; o; o >>= 1) {
        if (t < o) red[t] += red[t + o];
        __syncthreads();
    }
    float var = red[0] / 200.f;
    float rstd = rsqrtf(var + 1e-6f);
    __syncthreads();
    if (t < 200) pool[t] = (pool[t] - mean) * rstd * g[t] + bb[t];
    __syncthreads();
    if (t < 4) {
        float acc = hb[t];
        for (int d2 = 0; d2 < 200; d2++) acc += pool[d2] * hw[t * 200 + d2];
        out[b * 4 + t] = acc;
    }
}

extern "C" void kernel_launch(void* const* d_in, const int* in_sizes, int n_in,
                              void* d_out, int out_size, void* d_ws, size_t ws_size,
                              hipStream_t stream) {
    const float* x        = (const float*)d_in[0];
    const float* conv1_w  = (const float*)d_in[1];
    const float* conv1_b  = (const float*)d_in[2];
    const float* gn1_g    = (const float*)d_in[3];
    const float* gn1_b    = (const float*)d_in[4];
    const float* conv2_w  = (const float*)d_in[5];
    const float* conv2_b  = (const float*)d_in[6];
    const float* gn2_g    = (const float*)d_in[7];
    const float* gn2_b    = (const float*)d_in[8];
    const float* conv3_w  = (const float*)d_in[9];
    const float* conv3_b  = (const float*)d_in[10];
    const float* gn3_g    = (const float*)d_in[11];
    const float* gn3_b    = (const float*)d_in[12];
    const float* cls_tok  = (const float*)d_in[13];
    const float* pos_emb  = (const float*)d_in[14];
    const float* time_emb = (const float*)d_in[15];
    const float* ln1_g    = (const float*)d_in[16];
    const float* ln1_b    = (const float*)d_in[17];
    const float* qkv_w    = (const float*)d_in[18];
    const float* rel_tab  = (const float*)d_in[19];
    const float* proj_w   = (const float*)d_in[20];
    const float* proj_b   = (const float*)d_in[21];
    const float* gamma1   = (const float*)d_in[22];
    const float* ln2_g    = (const float*)d_in[23];
    const float* ln2_b    = (const float*)d_in[24];
    const float* fc1_w    = (const float*)d_in[25];
    const float* fc1_b    = (const float*)d_in[26];
    const float* fc2_w    = (const float*)d_in[27];
    const float* fc2_b    = (const float*)d_in[28];
    const float* gamma2   = (const float*)d_in[29];
    const float* fcn_g    = (const float*)d_in[30];
    const float* fcn_b    = (const float*)d_in[31];
    const float* head_w   = (const float*)d_in[32];
    const float* head_b   = (const float*)d_in[33];
    const int*   rel_idx  = (const int*)d_in[34];

    float* ws = (float*)d_ws;
    float* h    = ws;                    // 8*513*200 = 820800
    float* y    = h + 820800;            // 820800
    float* qkvb = y + 820800;            // 4104*600 = 2462400
    float* ob   = qkvb + 2462400;        // 820800
    float* mlp  = ob + 820800;           // 4104*800 = 3283200
    float* stats = mlp + 3283200;        // 64
    // conv scratch aliases qkvb/mlp (used only before the transformer layers)
    float* c1 = qkvb;                    // 819200
    float* c2 = mlp;                     // 819200

    // ---- patch embed ----
    conv1_kernel<<<3200, 256, 0, stream>>>(x, conv1_w, conv1_b, c1);
    gn_stats_kernel<<<32, 256, 0, stream>>>(c1, stats);
    gn_apply_kernel<<<3200, 256, 0, stream>>>(c1, stats, gn1_g, gn1_b);
    conv3x1_kernel<<<3200, 256, 0, stream>>>(c1, conv2_w, conv2_b, c2);
    gn_stats_kernel<<<32, 256, 0, stream>>>(c2, stats);
    gn_apply_kernel<<<3200, 256, 0, stream>>>(c2, stats, gn2_g, gn2_b);
    conv3x1_kernel<<<3200, 256, 0, stream>>>(c2, conv3_w, conv3_b, c1);
    gn_stats_kernel<<<32, 256, 0, stream>>>(c1, stats);
    gn_apply_kernel<<<3200, 256, 0, stream>>>(c1, stats, gn3_g, gn3_b);
    embed_kernel<<<(820800 + 255) / 256, 256, 0, stream>>>(c1, cls_tok, pos_emb, time_emb, h);

    // ---- transformer layers ----
    for (int d = 0; d < 12; d++) {
        ln_kernel<<<4104, 64, 0, stream>>>(h, ln1_g + d * 200, ln1_b + d * 200, y);
        gemm_nt<0><<<dim3(10, 65), 256, 0, stream>>>(y, qkv_w + d * 120000, qkvb,
                                                     nullptr, nullptr, nullptr, 4104, 600, 200);
        attn_kernel<<<41040, 64, 0, stream>>>(qkvb, rel_tab + d * 19080, rel_idx, ob);
        gemm_nt<1><<<dim3(4, 65), 256, 0, stream>>>(ob, proj_w + d * 40000, h,
                                                    h, proj_b + d * 200, gamma1 + d * 200, 4104, 200, 200);
        ln_kernel<<<4104, 64, 0, stream>>>(h, ln2_g + d * 200, ln2_b + d * 200, y);
        gemm_nt<2><<<dim3(13, 65), 256, 0, stream>>>(y, fc1_w + d * 160000, mlp,
                                                     nullptr, fc1_b + d * 800, nullptr, 4104, 800, 200);
        gemm_nt<1><<<dim3(4, 65), 256, 0, stream>>>(mlp, fc2_w + d * 160000, h,
                                                    h, fc2_b + d * 200, gamma2 + d * 200, 4104, 200, 800);
    }

    // ---- pool + head ----
    final_kernel<<<8, 256, 0, stream>>>(h, fcn_g, fcn_b, head_w, head_b, (float*)d_out);
}

// Round 2
// 5058.186 us; speedup vs baseline: 1.3510x; 1.3510x over previous
//
#include <hip/hip_runtime.h>
#include <math.h>

#define DEV static __device__ __forceinline__

DEV float gelu_exact(float x) {
    return 0.5f * x * (1.0f + erff(x * 0.70710678118654752f));
}

// ---------------- conv1: (B,1,512,200) -> (B,8,512,25), k=15 stride=8 pad=7 ----------------
__global__ void conv1_kernel(const float* __restrict__ x, const float* __restrict__ w,
                             const float* __restrict__ bias, float* __restrict__ out) {
    int idx = blockIdx.x * blockDim.x + threadIdx.x;
    const int total = 8 * 8 * 512 * 25;
    if (idx >= total) return;
    int ow = idx % 25;
    int p  = (idx / 25) % 512;
    int oc = (idx / (25 * 512)) % 8;
    int b  = idx / (25 * 512 * 8);
    const float* xp = x + b * 512 * 200 + p * 200;
    const float* wp = w + oc * 15;
    float acc = bias[oc];
    int t0 = ow * 8 - 7;
#pragma unroll
    for (int k = 0; k < 15; k++) {
        int t = t0 + k;
        if (t >= 0 && t < 200) acc += wp[k] * xp[t];
    }
    out[idx] = acc;
}

// ---------------- conv 1x3 (pad 1) on (B,8,512,25) ----------------
__global__ void conv3x1_kernel(const float* __restrict__ in, const float* __restrict__ w,
                               const float* __restrict__ bias, float* __restrict__ out) {
    int idx = blockIdx.x * blockDim.x + threadIdx.x;
    const int total = 8 * 8 * 512 * 25;
    if (idx >= total) return;
    int ow = idx % 25;
    int p  = (idx / 25) % 512;
    int oc = (idx / 12800) & 7;
    int b  = idx / 102400;
    float acc = bias[oc];
#pragma unroll
    for (int ic = 0; ic < 8; ic++) {
        const float* ip = in + b * 102400 + ic * 12800 + p * 25;
        const float* wp = w + oc * 24 + ic * 3;
        if (ow > 0)  acc += wp[0] * ip[ow - 1];
        acc += wp[1] * ip[ow];
        if (ow < 24) acc += wp[2] * ip[ow + 1];
    }
    out[idx] = acc;
}

// ---------------- groupnorm stats: one block per (b, group) ----------------
__global__ void gn_stats_kernel(const float* __restrict__ buf, float* __restrict__ stats) {
    int b = blockIdx.x >> 2, g = blockIdx.x & 3;
    const float* base = buf + b * 102400 + g * 2 * 12800;
    float s = 0.f, s2 = 0.f;
    for (int l = threadIdx.x; l < 25600; l += 256) {
        float v = base[l];
        s += v; s2 += v * v;
    }
    __shared__ float ss[256], ss2[256];
    ss[threadIdx.x] = s; ss2[threadIdx.x] = s2;
    __syncthreads();
    for (int o = 128; o; o >>= 1) {
        if (threadIdx.x < o) { ss[threadIdx.x] += ss[threadIdx.x + o]; ss2[threadIdx.x] += ss2[threadIdx.x + o]; }
        __syncthreads();
    }
    if (threadIdx.x == 0) {
        float m = ss[0] / 25600.f;
        float v = ss2[0] / 25600.f - m * m;
        stats[blockIdx.x * 2] = m;
        stats[blockIdx.x * 2 + 1] = v;
    }
}

__global__ void gn_apply_kernel(float* __restrict__ buf, const float* __restrict__ stats,
                                const float* __restrict__ g, const float* __restrict__ bb) {
    int idx = blockIdx.x * blockDim.x + threadIdx.x;
    if (idx >= 8 * 102400) return;
    int c = (idx / 12800) & 7;
    int b = idx / 102400;
    int grp = c >> 1;
    float m = stats[(b * 4 + grp) * 2];
    float v = stats[(b * 4 + grp) * 2 + 1];
    float val = (buf[idx] - m) * rsqrtf(v + 1e-5f) * g[c] + bb[c];
    buf[idx] = gelu_exact(val);
}

// ---------------- embed: conv(B,8,512,25) -> h(B,513,200) + cls + pos + time ----------------
__global__ void embed_kernel(const float* __restrict__ conv, const float* __restrict__ cls,
                             const float* __restrict__ pos, const float* __restrict__ te,
                             float* __restrict__ h) {
    int idx = blockIdx.x * blockDim.x + threadIdx.x;
    if (idx >= 8 * 513 * 200) return;
    int d = idx % 200;
    int n = (idx / 200) % 513;
    int b = idx / (200 * 513);
    float val;
    if (n == 0) {
        val = cls[d] + pos[d];
    } else {
        int p = n - 1;
        int t = d >> 3;   // 0..24  (feature = t*8 + c)
        int c = d & 7;
        val = conv[b * 102400 + c * 12800 + p * 25 + t];
        int ch = p >> 3, tw = p & 7;
        val += pos[(1 + ch) * 200 + d] + te[tw * 200 + d];
    }
    h[idx] = val;
}

// ---------------- LayerNorm over D=200, one wave per row ----------------
__global__ __launch_bounds__(64) void ln_kernel(const float* __restrict__ in,
                                                const float* __restrict__ g,
                                                const float* __restrict__ b,
                                                float* __restrict__ out) {
    int row = blockIdx.x;
    int lane = threadIdx.x;
    const float* x = in + row * 200;
    float v[4];
    float s = 0.f;
#pragma unroll
    for (int i = 0; i < 4; i++) {
        int d = lane + i * 64;
        v[i] = (d < 200) ? x[d] : 0.f;
        s += v[i];
    }
#pragma unroll
    for (int o = 32; o; o >>= 1) s += __shfl_xor(s, o);
    float mean = s * (1.f / 200.f);
    float s2 = 0.f;
#pragma unroll
    for (int i = 0; i < 4; i++) {
        int d = lane + i * 64;
        float dv = (d < 200) ? (v[i] - mean) : 0.f;
        s2 += dv * dv;
    }
#pragma unroll
    for (int o = 32; o; o >>= 1) s2 += __shfl_xor(s2, o);
    float rstd = rsqrtf(s2 * (1.f / 200.f) + 1e-6f);
#pragma unroll
    for (int i = 0; i < 4; i++) {
        int d = lane + i * 64;
        if (d < 200) out[row * 200 + d] = (v[i] - mean) * rstd * g[d] + b[d];
    }
}

// ---------------- tiled GEMM: C[M,N] = A[M,K] @ W[N,K]^T  (+ epilogue) ----------------
template <int EPI>
__global__ __launch_bounds__(256) void gemm_nt(const float* __restrict__ A,
                                               const float* __restrict__ W,
                                               float* __restrict__ C,
                                               const float* __restrict__ res,
                                               const float* __restrict__ bias,
                                               const float* __restrict__ gamma,
                                               int M, int N, int K) {
    __shared__ float As[16][65];
    __shared__ float Ws[16][65];
    int tx = threadIdx.x & 15, ty = threadIdx.x >> 4;
    int bm = blockIdx.y * 64, bn = blockIdx.x * 64;
    float acc[4][4] = {};
    for (int k0 = 0; k0 < K; k0 += 16) {
        for (int l = threadIdx.x; l < 64 * 16; l += 256) {
            int m = l >> 4, k = l & 15;
            int gk = k0 + k;
            int gm = bm + m;
            int gn = bn + m;
            As[k][m] = (gm < M && gk < K) ? A[gm * K + gk] : 0.f;
            Ws[k][m] = (gn < N && gk < K) ? W[gn * K + gk] : 0.f;
        }
        __syncthreads();
#pragma unroll
        for (int k = 0; k < 16; k++) {
            float a[4], w[4];
#pragma unroll
            for (int i = 0; i < 4; i++) a[i] = As[k][ty * 4 + i];
#pragma unroll
            for (int j = 0; j < 4; j++) w[j] = Ws[k][tx * 4 + j];
#pragma unroll
            for (int i = 0; i < 4; i++)
#pragma unroll
                for (int j = 0; j < 4; j++) acc[i][j] += a[i] * w[j];
        }
        __syncthreads();
    }
#pragma unroll
    for (int i = 0; i < 4; i++) {
        int gm = bm + ty * 4 + i;
        if (gm >= M) continue;
#pragma unroll
        for (int j = 0; j < 4; j++) {
            int gn = bn + tx * 4 + j;
            if (gn >= N) continue;
            float v = acc[i][j];
            if (EPI == 0) {
                C[gm * N + gn] = v;
            } else if (EPI == 1) {
                C[gm * N + gn] = res[gm * N + gn] + gamma[gn] * (v + bias[gn]);
            } else {
                C[gm * N + gn] = gelu_exact(v + bias[gn]);
            }
        }
    }
}

// ---------------- flash attention: one block per (b, h, 64-query tile) ----------------
// 256 threads. thread t: query q = t>>2 (tile-local), key-chunk / dim-chunk = t&3.
// LDS: Qs/Ks/Vs [64][20], Ps [64][65]. Online softmax, rel-pos bias gathered inline.
__global__ __launch_bounds__(256) void attn_flash_kernel(const float* __restrict__ qkv,
                                                         const float* __restrict__ table,
                                                         const int* __restrict__ ridx,
                                                         float* __restrict__ ob) {
    __shared__ float Qs[64][20];
    __shared__ float Ks[64][20];
    __shared__ float Vs[64][20];
    __shared__ float Ps[64][65];

    const int qt = blockIdx.x;      // 0..8
    const int hh = blockIdx.y;      // 0..9
    const int b  = blockIdx.z;      // 0..7
    const int t  = threadIdx.x;
    const int q  = t >> 2;          // 0..63 tile-local query
    const int sub = t & 3;          // 0..3
    const int n  = qt * 64 + q;     // global query index
    const bool qvalid = (n < 513);
    const float scale = 0.22360679774997896f; // 1/sqrt(20)

    // load Q tile (pre-scaled)
    for (int l = t; l < 64 * 20; l += 256) {
        int qq = l / 20, i = l % 20;
        int gn = qt * 64 + qq;
        Qs[qq][i] = (gn < 513) ? qkv[(b * 513 + gn) * 600 + hh * 20 + i] * scale : 0.f;
    }

    float m = -1e30f;   // running max (replicated across the 4 lanes of a q-group)
    float lsum = 0.f;   // running denom
    float acc[5] = {};  // output dims d0..d0+4, d0 = sub*5
    const int d0 = sub * 5;
    const int krow_base = n * 513;  // ridx row

    for (int kt = 0; kt < 9; kt++) {
        __syncthreads();  // protect Ks/Vs from previous iteration's readers
        // load K,V tiles
        for (int l = t; l < 64 * 20; l += 256) {
            int kk = l / 20, i = l % 20;
            int gk = kt * 64 + kk;
            if (gk < 513) {
                const float* base = qkv + (b * 513 + gk) * 600 + hh * 20 + i;
                Ks[kk][i] = base[200];
                Vs[kk][i] = base[400];
            } else {
                Ks[kk][i] = 0.f;
                Vs[kk][i] = 0.f;
            }
        }
        __syncthreads();

        // scores for 16 keys
        float s[16];
        float tm = -1e30f;
#pragma unroll
        for (int kk = 0; kk < 16; kk++) {
            int klocal = sub * 16 + kk;
            int gk = kt * 64 + klocal;
            float sv = -1e30f;
            if (qvalid && gk < 513) {
                sv = table[ridx[krow_base + gk] * 10 + hh];
#pragma unroll
                for (int i = 0; i < 20; i++) sv += Qs[q][i] * Ks[klocal][i];
            }
            s[kk] = sv;
            tm = fmaxf(tm, sv);
        }
        // row max across the 4-lane group
        tm = fmaxf(tm, __shfl_xor(tm, 1));
        tm = fmaxf(tm, __shfl_xor(tm, 2));
        float m_new = fmaxf(m, tm);
        float rescale = __expf(m - m_new);
        m = m_new;

        float ts = 0.f;
#pragma unroll
        for (int kk = 0; kk < 16; kk++) {
            float p = __expf(s[kk] - m_new);
            ts += p;
            Ps[q][sub * 16 + kk] = p;
        }
        ts += __shfl_xor(ts, 1);
        ts += __shfl_xor(ts, 2);
        lsum = lsum * rescale + ts;
#pragma unroll
        for (int j = 0; j < 5; j++) acc[j] *= rescale;

        __syncthreads();  // Ps written

        // PV: acc[j] += sum_k Ps[q][k] * Vs[k][d0+j]
        for (int k = 0; k < 64; k++) {
            float p = Ps[q][k];
#pragma unroll
            for (int j = 0; j < 5; j++) acc[j] += p * Vs[k][d0 + j];
        }
    }

    if (qvalid) {
        float inv = 1.f / lsum;
        float* op = ob + (b * 513 + n) * 200 + hh * 20 + d0;
#pragma unroll
        for (int j = 0; j < 5; j++) op[j] = acc[j] * inv;
    }
}

// ---------------- final: mean-pool patches -> LN -> head (200 -> 4) ----------------
__global__ __launch_bounds__(256) void final_kernel(const float* __restrict__ h,
                                                    const float* __restrict__ g,
                                                    const float* __restrict__ bb,
                                                    const float* __restrict__ hw,
                                                    const float* __restrict__ hb,
                                                    float* __restrict__ out) {
    __shared__ float pool[256];
    __shared__ float red[256];
    int b = blockIdx.x, t = threadIdx.x;
    float s = 0.f;
    if (t < 200) {
        const float* hp = h + b * 513 * 200 + 200 + t;
        for (int p = 0; p < 512; p++) s += hp[p * 200];
        s *= (1.f / 512.f);
    }
    pool[t] = (t < 200) ? s : 0.f;
    red[t] = pool[t];
    __syncthreads();
    for (int o = 128; o; o >>= 1) {
        if (t < o) red[t] += red[t + o];
        __syncthreads();
    }
    float mean = red[0] / 200.f;
    __syncthreads();
    float dv = (t < 200) ? (pool[t] - mean) : 0.f;
    red[t] = dv * dv;
    __syncthreads();
    for (int o = 128; o; o >>= 1) {
        if (t < o) red[t] += red[t + o];
        __syncthreads();
    }
    float var = red[0] / 200.f;
    float rstd = rsqrtf(var + 1e-6f);
    __syncthreads();
    if (t < 200) pool[t] = (pool[t] - mean) * rstd * g[t] + bb[t];
    __syncthreads();
    if (t < 4) {
        float acc = hb[t];
        for (int d2 = 0; d2 < 200; d2++) acc += pool[d2] * hw[t * 200 + d2];
        out[b * 4 + t] = acc;
    }
}

extern "C" void kernel_launch(void* const* d_in, const int* in_sizes, int n_in,
                              void* d_out, int out_size, void* d_ws, size_t ws_size,
                              hipStream_t stream) {
    const float* x        = (const float*)d_in[0];
    const float* conv1_w  = (const float*)d_in[1];
    const float* conv1_b  = (const float*)d_in[2];
    const float* gn1_g    = (const float*)d_in[3];
    const float* gn1_b    = (const float*)d_in[4];
    const float* conv2_w  = (const float*)d_in[5];
    const float* conv2_b  = (const float*)d_in[6];
    const float* gn2_g    = (const float*)d_in[7];
    const float* gn2_b    = (const float*)d_in[8];
    const float* conv3_w  = (const float*)d_in[9];
    const float* conv3_b  = (const float*)d_in[10];
    const float* gn3_g    = (const float*)d_in[11];
    const float* gn3_b    = (const float*)d_in[12];
    const float* cls_tok  = (const float*)d_in[13];
    const float* pos_emb  = (const float*)d_in[14];
    const float* time_emb = (const float*)d_in[15];
    const float* ln1_g    = (const float*)d_in[16];
    const float* ln1_b    = (const float*)d_in[17];
    const float* qkv_w    = (const float*)d_in[18];
    const float* rel_tab  = (const float*)d_in[19];
    const float* proj_w   = (const float*)d_in[20];
    const float* proj_b   = (const float*)d_in[21];
    const float* gamma1   = (const float*)d_in[22];
    const float* ln2_g    = (const float*)d_in[23];
    const float* ln2_b    = (const float*)d_in[24];
    const float* fc1_w    = (const float*)d_in[25];
    const float* fc1_b    = (const float*)d_in[26];
    const float* fc2_w    = (const float*)d_in[27];
    const float* fc2_b    = (const float*)d_in[28];
    const float* gamma2   = (const float*)d_in[29];
    const float* fcn_g    = (const float*)d_in[30];
    const float* fcn_b    = (const float*)d_in[31];
    const float* head_w   = (const float*)d_in[32];
    const float* head_b   = (const float*)d_in[33];
    const int*   rel_idx  = (const int*)d_in[34];

    float* ws = (float*)d_ws;
    float* h    = ws;                    // 8*513*200 = 820800
    float* y    = h + 820800;            // 820800
    float* qkvb = y + 820800;            // 4104*600 = 2462400
    float* ob   = qkvb + 2462400;        // 820800
    float* mlp  = ob + 820800;           // 4104*800 = 3283200
    float* stats = mlp + 3283200;        // 64
    float* c1 = qkvb;                    // conv scratch (aliased, pre-transformer only)
    float* c2 = mlp;

    // ---- patch embed ----
    conv1_kernel<<<3200, 256, 0, stream>>>(x, conv1_w, conv1_b, c1);
    gn_stats_kernel<<<32, 256, 0, stream>>>(c1, stats);
    gn_apply_kernel<<<3200, 256, 0, stream>>>(c1, stats, gn1_g, gn1_b);
    conv3x1_kernel<<<3200, 256, 0, stream>>>(c1, conv2_w, conv2_b, c2);
    gn_stats_kernel<<<32, 256, 0, stream>>>(c2, stats);
    gn_apply_kernel<<<3200, 256, 0, stream>>>(c2, stats, gn2_g, gn2_b);
    conv3x1_kernel<<<3200, 256, 0, stream>>>(c2, conv3_w, conv3_b, c1);
    gn_stats_kernel<<<32, 256, 0, stream>>>(c1, stats);
    gn_apply_kernel<<<3200, 256, 0, stream>>>(c1, stats, gn3_g, gn3_b);
    embed_kernel<<<(820800 + 255) / 256, 256, 0, stream>>>(c1, cls_tok, pos_emb, time_emb, h);

    // ---- transformer layers ----
    for (int d = 0; d < 12; d++) {
        ln_kernel<<<4104, 64, 0, stream>>>(h, ln1_g + d * 200, ln1_b + d * 200, y);
        gemm_nt<0><<<dim3(10, 65), 256, 0, stream>>>(y, qkv_w + d * 120000, qkvb,
                                                     nullptr, nullptr, nullptr, 4104, 600, 200);
        attn_flash_kernel<<<dim3(9, 10, 8), 256, 0, stream>>>(qkvb, rel_tab + d * 19080, rel_idx, ob);
        gemm_nt<1><<<dim3(4, 65), 256, 0, stream>>>(ob, proj_w + d * 40000, h,
                                                    h, proj_b + d * 200, gamma1 + d * 200, 4104, 200, 200);
        ln_kernel<<<4104, 64, 0, stream>>>(h, ln2_g + d * 200, ln2_b + d * 200, y);
        gemm_nt<2><<<dim3(13, 65), 256, 0, stream>>>(y, fc1_w + d * 160000, mlp,
                                                     nullptr, fc1_b + d * 800, nullptr, 4104, 800, 200);
        gemm_nt<1><<<dim3(4, 65), 256, 0, stream>>>(mlp, fc2_w + d * 160000, h,
                                                    h, fc2_b + d * 200, gamma2 + d * 200, 4104, 200, 800);
    }

    // ---- pool + head ----
    final_kernel<<<8, 256, 0, stream>>>(h, fcn_g, fcn_b, head_w, head_b, (float*)d_out);
}

// Round 3
// 3919.870 us; speedup vs baseline: 1.7434x; 1.2904x over previous
//
#include <hip/hip_runtime.h>
#include <math.h>

#define DEV static __device__ __forceinline__

typedef __attribute__((ext_vector_type(8))) short bf16x8;
typedef __attribute__((ext_vector_type(4))) float f32x4;

DEV float gelu_exact(float x) {
    return 0.5f * x * (1.0f + erff(x * 0.70710678118654752f));
}

DEV short f2bf(float f) {
    union { float f; unsigned u; } v; v.f = f;
    unsigned r = v.u + 0x7FFF + ((v.u >> 16) & 1);  // round-to-nearest-even
    return (short)(r >> 16);
}

// ---------------- conv1: (B,1,512,200) -> (B,8,512,25), k=15 stride=8 pad=7 ----------------
__global__ void conv1_kernel(const float* __restrict__ x, const float* __restrict__ w,
                             const float* __restrict__ bias, float* __restrict__ out) {
    int idx = blockIdx.x * blockDim.x + threadIdx.x;
    const int total = 8 * 8 * 512 * 25;
    if (idx >= total) return;
    int ow = idx % 25;
    int p  = (idx / 25) % 512;
    int oc = (idx / (25 * 512)) % 8;
    int b  = idx / (25 * 512 * 8);
    const float* xp = x + b * 512 * 200 + p * 200;
    const float* wp = w + oc * 15;
    float acc = bias[oc];
    int t0 = ow * 8 - 7;
#pragma unroll
    for (int k = 0; k < 15; k++) {
        int t = t0 + k;
        if (t >= 0 && t < 200) acc += wp[k] * xp[t];
    }
    out[idx] = acc;
}

// ---------------- conv 1x3 (pad 1) on (B,8,512,25) ----------------
__global__ void conv3x1_kernel(const float* __restrict__ in, const float* __restrict__ w,
                               const float* __restrict__ bias, float* __restrict__ out) {
    int idx = blockIdx.x * blockDim.x + threadIdx.x;
    const int total = 8 * 8 * 512 * 25;
    if (idx >= total) return;
    int ow = idx % 25;
    int p  = (idx / 25) % 512;
    int oc = (idx / 12800) & 7;
    int b  = idx / 102400;
    float acc = bias[oc];
#pragma unroll
    for (int ic = 0; ic < 8; ic++) {
        const float* ip = in + b * 102400 + ic * 12800 + p * 25;
        const float* wp = w + oc * 24 + ic * 3;
        if (ow > 0)  acc += wp[0] * ip[ow - 1];
        acc += wp[1] * ip[ow];
        if (ow < 24) acc += wp[2] * ip[ow + 1];
    }
    out[idx] = acc;
}

// ---------------- groupnorm stats: one block per (b, group) ----------------
__global__ void gn_stats_kernel(const float* __restrict__ buf, float* __restrict__ stats) {
    int b = blockIdx.x >> 2, g = blockIdx.x & 3;
    const float* base = buf + b * 102400 + g * 2 * 12800;
    float s = 0.f, s2 = 0.f;
    for (int l = threadIdx.x; l < 25600; l += 256) {
        float v = base[l];
        s += v; s2 += v * v;
    }
    __shared__ float ss[256], ss2[256];
    ss[threadIdx.x] = s; ss2[threadIdx.x] = s2;
    __syncthreads();
    for (int o = 128; o; o >>= 1) {
        if (threadIdx.x < o) { ss[threadIdx.x] += ss[threadIdx.x + o]; ss2[threadIdx.x] += ss2[threadIdx.x + o]; }
        __syncthreads();
    }
    if (threadIdx.x == 0) {
        float m = ss[0] / 25600.f;
        float v = ss2[0] / 25600.f - m * m;
        stats[blockIdx.x * 2] = m;
        stats[blockIdx.x * 2 + 1] = v;
    }
}

__global__ void gn_apply_kernel(float* __restrict__ buf, const float* __restrict__ stats,
                                const float* __restrict__ g, const float* __restrict__ bb) {
    int idx = blockIdx.x * blockDim.x + threadIdx.x;
    if (idx >= 8 * 102400) return;
    int c = (idx / 12800) & 7;
    int b = idx / 102400;
    int grp = c >> 1;
    float m = stats[(b * 4 + grp) * 2];
    float v = stats[(b * 4 + grp) * 2 + 1];
    float val = (buf[idx] - m) * rsqrtf(v + 1e-5f) * g[c] + bb[c];
    buf[idx] = gelu_exact(val);
}

// ---------------- embed ----------------
__global__ void embed_kernel(const float* __restrict__ conv, const float* __restrict__ cls,
                             const float* __restrict__ pos, const float* __restrict__ te,
                             float* __restrict__ h) {
    int idx = blockIdx.x * blockDim.x + threadIdx.x;
    if (idx >= 8 * 513 * 200) return;
    int d = idx % 200;
    int n = (idx / 200) % 513;
    int b = idx / (200 * 513);
    float val;
    if (n == 0) {
        val = cls[d] + pos[d];
    } else {
        int p = n - 1;
        int t = d >> 3;
        int c = d & 7;
        val = conv[b * 102400 + c * 12800 + p * 25 + t];
        int ch = p >> 3, tw = p & 7;
        val += pos[(1 + ch) * 200 + d] + te[tw * 200 + d];
    }
    h[idx] = val;
}

// ---------------- LayerNorm over D=200, one wave per row ----------------
__global__ __launch_bounds__(64) void ln_kernel(const float* __restrict__ in,
                                                const float* __restrict__ g,
                                                const float* __restrict__ b,
                                                float* __restrict__ out) {
    int row = blockIdx.x;
    int lane = threadIdx.x;
    const float* x = in + row * 200;
    float v[4];
    float s = 0.f;
#pragma unroll
    for (int i = 0; i < 4; i++) {
        int d = lane + i * 64;
        v[i] = (d < 200) ? x[d] : 0.f;
        s += v[i];
    }
#pragma unroll
    for (int o = 32; o; o >>= 1) s += __shfl_xor(s, o);
    float mean = s * (1.f / 200.f);
    float s2 = 0.f;
#pragma unroll
    for (int i = 0; i < 4; i++) {
        int d = lane + i * 64;
        float dv = (d < 200) ? (v[i] - mean) : 0.f;
        s2 += dv * dv;
    }
#pragma unroll
    for (int o = 32; o; o >>= 1) s2 += __shfl_xor(s2, o);
    float rstd = rsqrtf(s2 * (1.f / 200.f) + 1e-6f);
#pragma unroll
    for (int i = 0; i < 4; i++) {
        int d = lane + i * 64;
        if (d < 200) out[row * 200 + d] = (v[i] - mean) * rstd * g[d] + b[d];
    }
}

// ---------------- MFMA GEMM: C[M,N] = A[M,K] @ W[N,K]^T (+ epilogue) ----------------
// bf16 MFMA 16x16x32, fp32 accumulate. BM=128, BN=128, BK=64, 4 waves (2x2),
// wave tile 64x64 (4x4 fragments). fp32 inputs converted to bf16 during staging.
// EPI 0: C = acc ;  EPI 1: C = res + gamma[n]*(acc+bias[n]) ;  EPI 2: C = gelu(acc+bias[n])
template <int EPI>
__global__ __launch_bounds__(256) void gemm_mfma(const float* __restrict__ A,
                                                 const float* __restrict__ W,
                                                 float* __restrict__ C,
                                                 const float* __restrict__ res,
                                                 const float* __restrict__ bias,
                                                 const float* __restrict__ gamma,
                                                 int M, int N, int K) {
    constexpr int LDR = 72;  // padded LDS row (bf16 elems): 144B stride -> 2-way banks only
    __shared__ __align__(16) short As[128 * LDR];
    __shared__ __align__(16) short Bs[128 * LDR];

    const int tid = threadIdx.x;
    const int wave = tid >> 6;
    const int lane = tid & 63;
    const int wm = (wave >> 1) * 64;
    const int wn = (wave & 1) * 64;
    const int bm = blockIdx.y * 128;
    const int bn = blockIdx.x * 128;

    const int srow = tid >> 3;          // 0..31
    const int sk = (tid & 7) * 8;       // 0..56

    f32x4 acc[4][4] = {};

    for (int k0 = 0; k0 < K; k0 += 64) {
        __syncthreads();
        const bool kfull = (k0 + 64 <= K);
#pragma unroll
        for (int rr = 0; rr < 4; rr++) {
            int row = srow + rr * 32;
            // ---- A ----
            {
                int gm = bm + row;
                bf16x8 pack;
                if (gm < M && kfull) {
                    const float4* p = (const float4*)(A + (size_t)gm * K + k0 + sk);
                    float4 f0 = p[0], f1 = p[1];
                    pack[0] = f2bf(f0.x); pack[1] = f2bf(f0.y);
                    pack[2] = f2bf(f0.z); pack[3] = f2bf(f0.w);
                    pack[4] = f2bf(f1.x); pack[5] = f2bf(f1.y);
                    pack[6] = f2bf(f1.z); pack[7] = f2bf(f1.w);
                } else {
#pragma unroll
                    for (int e = 0; e < 8; e++) {
                        int gk = k0 + sk + e;
                        pack[e] = (gm < M && gk < K) ? f2bf(A[(size_t)gm * K + gk]) : (short)0;
                    }
                }
                *(bf16x8*)&As[row * LDR + sk] = pack;
            }
            // ---- B (= W rows) ----
            {
                int gn = bn + row;
                bf16x8 pack;
                if (gn < N && kfull) {
                    const float4* p = (const float4*)(W + (size_t)gn * K + k0 + sk);
                    float4 f0 = p[0], f1 = p[1];
                    pack[0] = f2bf(f0.x); pack[1] = f2bf(f0.y);
                    pack[2] = f2bf(f0.z); pack[3] = f2bf(f0.w);
                    pack[4] = f2bf(f1.x); pack[5] = f2bf(f1.y);
                    pack[6] = f2bf(f1.z); pack[7] = f2bf(f1.w);
                } else {
#pragma unroll
                    for (int e = 0; e < 8; e++) {
                        int gk = k0 + sk + e;
                        pack[e] = (gn < N && gk < K) ? f2bf(W[(size_t)gn * K + gk]) : (short)0;
                    }
                }
                *(bf16x8*)&Bs[row * LDR + sk] = pack;
            }
        }
        __syncthreads();

#pragma unroll
        for (int kk = 0; kk < 2; kk++) {
            const int kbase = kk * 32 + (lane >> 4) * 8;
            bf16x8 af[4], bfr[4];
#pragma unroll
            for (int i = 0; i < 4; i++)
                af[i] = *(const bf16x8*)&As[(wm + i * 16 + (lane & 15)) * LDR + kbase];
#pragma unroll
            for (int j = 0; j < 4; j++)
                bfr[j] = *(const bf16x8*)&Bs[(wn + j * 16 + (lane & 15)) * LDR + kbase];
#pragma unroll
            for (int i = 0; i < 4; i++)
#pragma unroll
                for (int j = 0; j < 4; j++)
                    acc[i][j] = __builtin_amdgcn_mfma_f32_16x16x32_bf16(af[i], bfr[j], acc[i][j], 0, 0, 0);
        }
    }

    // epilogue: C/D layout col = lane&15, row = (lane>>4)*4 + reg
    const int col0 = bn + wn + (lane & 15);
    const int rbase = (lane >> 4) * 4;
#pragma unroll
    for (int i = 0; i < 4; i++) {
#pragma unroll
        for (int r = 0; r < 4; r++) {
            int gm = bm + wm + i * 16 + rbase + r;
            if (gm >= M) continue;
#pragma unroll
            for (int j = 0; j < 4; j++) {
                int gn = col0 + j * 16;
                if (gn >= N) continue;
                float v = acc[i][j][r];
                if (EPI == 0) {
                    C[(size_t)gm * N + gn] = v;
                } else if (EPI == 1) {
                    C[(size_t)gm * N + gn] = res[(size_t)gm * N + gn] + gamma[gn] * (v + bias[gn]);
                } else {
                    C[(size_t)gm * N + gn] = gelu_exact(v + bias[gn]);
                }
            }
        }
    }
}

// ---------------- flash attention: one block per (b, h, 64-query tile) ----------------
// LDS tiles padded to 21 floats/row: Ks score-loop reads were 4-way same-bank
// (320*sub % 32 == 0); stride 21 -> 336 % 32 = 16 -> 2-way (free).
__global__ __launch_bounds__(256) void attn_flash_kernel(const float* __restrict__ qkv,
                                                         const float* __restrict__ table,
                                                         const int* __restrict__ ridx,
                                                         float* __restrict__ ob) {
    __shared__ float Qs[64][21];
    __shared__ float Ks[64][21];
    __shared__ float Vs[64][21];
    __shared__ float Ps[64][65];

    const int qt = blockIdx.x;
    const int hh = blockIdx.y;
    const int b  = blockIdx.z;
    const int t  = threadIdx.x;
    const int q  = t >> 2;
    const int sub = t & 3;
    const int n  = qt * 64 + q;
    const bool qvalid = (n < 513);
    const float scale = 0.22360679774997896f;

    for (int l = t; l < 64 * 20; l += 256) {
        int qq = l / 20, i = l % 20;
        int gn = qt * 64 + qq;
        Qs[qq][i] = (gn < 513) ? qkv[(b * 513 + gn) * 600 + hh * 20 + i] * scale : 0.f;
    }

    float m = -1e30f;
    float lsum = 0.f;
    float acc[5] = {};
    const int d0 = sub * 5;
    const int krow_base = n * 513;

    for (int kt = 0; kt < 9; kt++) {
        __syncthreads();
        for (int l = t; l < 64 * 20; l += 256) {
            int kk = l / 20, i = l % 20;
            int gk = kt * 64 + kk;
            if (gk < 513) {
                const float* base = qkv + (b * 513 + gk) * 600 + hh * 20 + i;
                Ks[kk][i] = base[200];
                Vs[kk][i] = base[400];
            } else {
                Ks[kk][i] = 0.f;
                Vs[kk][i] = 0.f;
            }
        }
        __syncthreads();

        float s[16];
        float tm = -1e30f;
#pragma unroll
        for (int kk = 0; kk < 16; kk++) {
            int klocal = sub * 16 + kk;
            int gk = kt * 64 + klocal;
            float sv = -1e30f;
            if (qvalid && gk < 513) {
                sv = table[ridx[krow_base + gk] * 10 + hh];
#pragma unroll
                for (int i = 0; i < 20; i++) sv += Qs[q][i] * Ks[klocal][i];
            }
            s[kk] = sv;
            tm = fmaxf(tm, sv);
        }
        tm = fmaxf(tm, __shfl_xor(tm, 1));
        tm = fmaxf(tm, __shfl_xor(tm, 2));
        float m_new = fmaxf(m, tm);
        float rescale = __expf(m - m_new);
        m = m_new;

        float ts = 0.f;
#pragma unroll
        for (int kk = 0; kk < 16; kk++) {
            float p = __expf(s[kk] - m_new);
            ts += p;
            Ps[q][sub * 16 + kk] = p;
        }
        ts += __shfl_xor(ts, 1);
        ts += __shfl_xor(ts, 2);
        lsum = lsum * rescale + ts;
#pragma unroll
        for (int j = 0; j < 5; j++) acc[j] *= rescale;

        __syncthreads();

        for (int k = 0; k < 64; k++) {
            float p = Ps[q][k];
#pragma unroll
            for (int j = 0; j < 5; j++) acc[j] += p * Vs[k][d0 + j];
        }
    }

    if (qvalid) {
        float inv = 1.f / lsum;
        float* op = ob + (b * 513 + n) * 200 + hh * 20 + d0;
#pragma unroll
        for (int j = 0; j < 5; j++) op[j] = acc[j] * inv;
    }
}

// ---------------- final: mean-pool patches -> LN -> head (200 -> 4) ----------------
__global__ __launch_bounds__(256) void final_kernel(const float* __restrict__ h,
                                                    const float* __restrict__ g,
                                                    const float* __restrict__ bb,
                                                    const float* __restrict__ hw,
                                                    const float* __restrict__ hb,
                                                    float* __restrict__ out) {
    __shared__ float pool[256];
    __shared__ float red[256];
    int b = blockIdx.x, t = threadIdx.x;
    float s = 0.f;
    if (t < 200) {
        const float* hp = h + b * 513 * 200 + 200 + t;
        for (int p = 0; p < 512; p++) s += hp[p * 200];
        s *= (1.f / 512.f);
    }
    pool[t] = (t < 200) ? s : 0.f;
    red[t] = pool[t];
    __syncthreads();
    for (int o = 128; o; o >>= 1) {
        if (t < o) red[t] += red[t + o];
        __syncthreads();
    }
    float mean = red[0] / 200.f;
    __syncthreads();
    float dv = (t < 200) ? (pool[t] - mean) : 0.f;
    red[t] = dv * dv;
    __syncthreads();
    for (int o = 128; o; o >>= 1) {
        if (t < o) red[t] += red[t + o];
        __syncthreads();
    }
    float var = red[0] / 200.f;
    float rstd = rsqrtf(var + 1e-6f);
    __syncthreads();
    if (t < 200) pool[t] = (pool[t] - mean) * rstd * g[t] + bb[t];
    __syncthreads();
    if (t < 4) {
        float acc = hb[t];
        for (int d2 = 0; d2 < 200; d2++) acc += pool[d2] * hw[t * 200 + d2];
        out[b * 4 + t] = acc;
    }
}

extern "C" void kernel_launch(void* const* d_in, const int* in_sizes, int n_in,
                              void* d_out, int out_size, void* d_ws, size_t ws_size,
                              hipStream_t stream) {
    const float* x        = (const float*)d_in[0];
    const float* conv1_w  = (const float*)d_in[1];
    const float* conv1_b  = (const float*)d_in[2];
    const float* gn1_g    = (const float*)d_in[3];
    const float* gn1_b    = (const float*)d_in[4];
    const float* conv2_w  = (const float*)d_in[5];
    const float* conv2_b  = (const float*)d_in[6];
    const float* gn2_g    = (const float*)d_in[7];
    const float* gn2_b    = (const float*)d_in[8];
    const float* conv3_w  = (const float*)d_in[9];
    const float* conv3_b  = (const float*)d_in[10];
    const float* gn3_g    = (const float*)d_in[11];
    const float* gn3_b    = (const float*)d_in[12];
    const float* cls_tok  = (const float*)d_in[13];
    const float* pos_emb  = (const float*)d_in[14];
    const float* time_emb = (const float*)d_in[15];
    const float* ln1_g    = (const float*)d_in[16];
    const float* ln1_b    = (const float*)d_in[17];
    const float* qkv_w    = (const float*)d_in[18];
    const float* rel_tab  = (const float*)d_in[19];
    const float* proj_w   = (const float*)d_in[20];
    const float* proj_b   = (const float*)d_in[21];
    const float* gamma1   = (const float*)d_in[22];
    const float* ln2_g    = (const float*)d_in[23];
    const float* ln2_b    = (const float*)d_in[24];
    const float* fc1_w    = (const float*)d_in[25];
    const float* fc1_b    = (const float*)d_in[26];
    const float* fc2_w    = (const float*)d_in[27];
    const float* fc2_b    = (const float*)d_in[28];
    const float* gamma2   = (const float*)d_in[29];
    const float* fcn_g    = (const float*)d_in[30];
    const float* fcn_b    = (const float*)d_in[31];
    const float* head_w   = (const float*)d_in[32];
    const float* head_b   = (const float*)d_in[33];
    const int*   rel_idx  = (const int*)d_in[34];

    float* ws = (float*)d_ws;
    float* h    = ws;                    // 820800
    float* y    = h + 820800;            // 820800
    float* qkvb = y + 820800;            // 2462400
    float* ob   = qkvb + 2462400;        // 820800
    float* mlp  = ob + 820800;           // 3283200
    float* stats = mlp + 3283200;        // 64
    float* c1 = qkvb;                    // conv scratch (aliased, pre-transformer only)
    float* c2 = mlp;

    // ---- patch embed ----
    conv1_kernel<<<3200, 256, 0, stream>>>(x, conv1_w, conv1_b, c1);
    gn_stats_kernel<<<32, 256, 0, stream>>>(c1, stats);
    gn_apply_kernel<<<3200, 256, 0, stream>>>(c1, stats, gn1_g, gn1_b);
    conv3x1_kernel<<<3200, 256, 0, stream>>>(c1, conv2_w, conv2_b, c2);
    gn_stats_kernel<<<32, 256, 0, stream>>>(c2, stats);
    gn_apply_kernel<<<3200, 256, 0, stream>>>(c2, stats, gn2_g, gn2_b);
    conv3x1_kernel<<<3200, 256, 0, stream>>>(c2, conv3_w, conv3_b, c1);
    gn_stats_kernel<<<32, 256, 0, stream>>>(c1, stats);
    gn_apply_kernel<<<3200, 256, 0, stream>>>(c1, stats, gn3_g, gn3_b);
    embed_kernel<<<(820800 + 255) / 256, 256, 0, stream>>>(c1, cls_tok, pos_emb, time_emb, h);

    // ---- transformer layers ----
    for (int d = 0; d < 12; d++) {
        ln_kernel<<<4104, 64, 0, stream>>>(h, ln1_g + d * 200, ln1_b + d * 200, y);
        gemm_mfma<0><<<dim3(5, 33), 256, 0, stream>>>(y, qkv_w + d * 120000, qkvb,
                                                      nullptr, nullptr, nullptr, 4104, 600, 200);
        attn_flash_kernel<<<dim3(9, 10, 8), 256, 0, stream>>>(qkvb, rel_tab + d * 19080, rel_idx, ob);
        gemm_mfma<1><<<dim3(2, 33), 256, 0, stream>>>(ob, proj_w + d * 40000, h,
                                                      h, proj_b + d * 200, gamma1 + d * 200, 4104, 200, 200);
        ln_kernel<<<4104, 64, 0, stream>>>(h, ln2_g + d * 200, ln2_b + d * 200, y);
        gemm_mfma<2><<<dim3(7, 33), 256, 0, stream>>>(y, fc1_w + d * 160000, mlp,
                                                      nullptr, fc1_b + d * 800, nullptr, 4104, 800, 200);
        gemm_mfma<1><<<dim3(2, 33), 256, 0, stream>>>(mlp, fc2_w + d * 160000, h,
                                                      h, fc2_b + d * 200, gamma2 + d * 200, 4104, 200, 800);
    }

    // ---- pool + head ----
    final_kernel<<<8, 256, 0, stream>>>(h, fcn_g, fcn_b, head_w, head_b, (float*)d_out);
}

// Round 4
// 2503.043 us; speedup vs baseline: 2.7302x; 1.5660x over previous
//
#include <hip/hip_runtime.h>
#include <math.h>

#define DEV static __device__ __forceinline__

typedef __attribute__((ext_vector_type(8))) short bf16x8;
typedef __attribute__((ext_vector_type(4))) float f32x4;

DEV float gelu_exact(float x) {
    return 0.5f * x * (1.0f + erff(x * 0.70710678118654752f));
}

DEV short f2bf(float f) {
    union { float f; unsigned u; } v; v.f = f;
    unsigned r = v.u + 0x7FFF + ((v.u >> 16) & 1);  // round-to-nearest-even
    return (short)(r >> 16);
}

DEV void gload_lds16(const void* g, void* lds) {
    __builtin_amdgcn_global_load_lds(
        (const __attribute__((address_space(1))) void*)g,
        (__attribute__((address_space(3))) void*)lds, 16, 0, 0);
}

// ---------------- conv1: (B,1,512,200) -> (B,8,512,25), k=15 stride=8 pad=7 ----------------
__global__ void conv1_kernel(const float* __restrict__ x, const float* __restrict__ w,
                             const float* __restrict__ bias, float* __restrict__ out) {
    int idx = blockIdx.x * blockDim.x + threadIdx.x;
    const int total = 8 * 8 * 512 * 25;
    if (idx >= total) return;
    int ow = idx % 25;
    int p  = (idx / 25) % 512;
    int oc = (idx / (25 * 512)) % 8;
    int b  = idx / (25 * 512 * 8);
    const float* xp = x + b * 512 * 200 + p * 200;
    const float* wp = w + oc * 15;
    float acc = bias[oc];
    int t0 = ow * 8 - 7;
#pragma unroll
    for (int k = 0; k < 15; k++) {
        int t = t0 + k;
        if (t >= 0 && t < 200) acc += wp[k] * xp[t];
    }
    out[idx] = acc;
}

// ---------------- conv 1x3 (pad 1) on (B,8,512,25) ----------------
__global__ void conv3x1_kernel(const float* __restrict__ in, const float* __restrict__ w,
                               const float* __restrict__ bias, float* __restrict__ out) {
    int idx = blockIdx.x * blockDim.x + threadIdx.x;
    const int total = 8 * 8 * 512 * 25;
    if (idx >= total) return;
    int ow = idx % 25;
    int p  = (idx / 25) % 512;
    int oc = (idx / 12800) & 7;
    int b  = idx / 102400;
    float acc = bias[oc];
#pragma unroll
    for (int ic = 0; ic < 8; ic++) {
        const float* ip = in + b * 102400 + ic * 12800 + p * 25;
        const float* wp = w + oc * 24 + ic * 3;
        if (ow > 0)  acc += wp[0] * ip[ow - 1];
        acc += wp[1] * ip[ow];
        if (ow < 24) acc += wp[2] * ip[ow + 1];
    }
    out[idx] = acc;
}

// ---------------- groupnorm stats ----------------
__global__ void gn_stats_kernel(const float* __restrict__ buf, float* __restrict__ stats) {
    int b = blockIdx.x >> 2, g = blockIdx.x & 3;
    const float* base = buf + b * 102400 + g * 2 * 12800;
    float s = 0.f, s2 = 0.f;
    for (int l = threadIdx.x; l < 25600; l += 256) {
        float v = base[l];
        s += v; s2 += v * v;
    }
    __shared__ float ss[256], ss2[256];
    ss[threadIdx.x] = s; ss2[threadIdx.x] = s2;
    __syncthreads();
    for (int o = 128; o; o >>= 1) {
        if (threadIdx.x < o) { ss[threadIdx.x] += ss[threadIdx.x + o]; ss2[threadIdx.x] += ss2[threadIdx.x + o]; }
        __syncthreads();
    }
    if (threadIdx.x == 0) {
        float m = ss[0] / 25600.f;
        float v = ss2[0] / 25600.f - m * m;
        stats[blockIdx.x * 2] = m;
        stats[blockIdx.x * 2 + 1] = v;
    }
}

__global__ void gn_apply_kernel(float* __restrict__ buf, const float* __restrict__ stats,
                                const float* __restrict__ g, const float* __restrict__ bb) {
    int idx = blockIdx.x * blockDim.x + threadIdx.x;
    if (idx >= 8 * 102400) return;
    int c = (idx / 12800) & 7;
    int b = idx / 102400;
    int grp = c >> 1;
    float m = stats[(b * 4 + grp) * 2];
    float v = stats[(b * 4 + grp) * 2 + 1];
    float val = (buf[idx] - m) * rsqrtf(v + 1e-5f) * g[c] + bb[c];
    buf[idx] = gelu_exact(val);
}

// ---------------- embed ----------------
__global__ void embed_kernel(const float* __restrict__ conv, const float* __restrict__ cls,
                             const float* __restrict__ pos, const float* __restrict__ te,
                             float* __restrict__ h) {
    int idx = blockIdx.x * blockDim.x + threadIdx.x;
    if (idx >= 8 * 513 * 200) return;
    int d = idx % 200;
    int n = (idx / 200) % 513;
    int b = idx / (200 * 513);
    float val;
    if (n == 0) {
        val = cls[d] + pos[d];
    } else {
        int p = n - 1;
        int t = d >> 3;
        int c = d & 7;
        val = conv[b * 102400 + c * 12800 + p * 25 + t];
        int ch = p >> 3, tw = p & 7;
        val += pos[(1 + ch) * 200 + d] + te[tw * 200 + d];
    }
    h[idx] = val;
}

// ---------------- weight convert+pad: fp32 [R][K] -> bf16 [R][KP] (zero pad) ----------------
__global__ void convpad_kernel(const float* __restrict__ src, short* __restrict__ dst,
                               int R, int K, int KP) {
    int idx = blockIdx.x * blockDim.x + threadIdx.x;
    if (idx >= R * KP) return;
    int r = idx / KP, c = idx % KP;
    dst[idx] = (c < K) ? f2bf(src[r * K + c]) : (short)0;
}

// ---------------- LayerNorm over D=200, one wave per row; bf16 [row][256] out ----------------
__global__ __launch_bounds__(64) void ln_kernel(const float* __restrict__ in,
                                                const float* __restrict__ g,
                                                const float* __restrict__ b,
                                                short* __restrict__ out) {
    int row = blockIdx.x;
    int lane = threadIdx.x;
    const float* x = in + row * 200;
    float v[4];
    float s = 0.f;
#pragma unroll
    for (int i = 0; i < 4; i++) {
        int d = lane + i * 64;
        v[i] = (d < 200) ? x[d] : 0.f;
        s += v[i];
    }
#pragma unroll
    for (int o = 32; o; o >>= 1) s += __shfl_xor(s, o);
    float mean = s * (1.f / 200.f);
    float s2 = 0.f;
#pragma unroll
    for (int i = 0; i < 4; i++) {
        int d = lane + i * 64;
        float dv = (d < 200) ? (v[i] - mean) : 0.f;
        s2 += dv * dv;
    }
#pragma unroll
    for (int o = 32; o; o >>= 1) s2 += __shfl_xor(s2, o);
    float rstd = rsqrtf(s2 * (1.f / 200.f) + 1e-6f);
#pragma unroll
    for (int i = 0; i < 4; i++) {
        int d = lane + i * 64;
        float val = (d < 200) ? (v[i] - mean) * rstd * g[d] + b[d] : 0.f;
        out[row * 256 + d] = f2bf(val);
    }
}

// ---------------- bf16 MFMA GEMM: C[M,N] = A[M,KP] @ W[N,KP]^T (+ epilogue) ----------------
// A,W pre-converted bf16, K zero-padded to KP (mult of 64). BM=BN=128, BK=64, 4 waves 2x2.
// Staging: global_load_lds dwordx4, linear LDS dest + inverse-XOR-swizzled source;
// ds_read_b128 with matching XOR -> 2-way banks (free).
// EPI 0: Cf = acc               (fp32, ldc)
// EPI 1: Cf = res + gamma[n]*(acc+bias[n])   (fp32 in-place residual)
// EPI 2: Cb = bf16(gelu(acc+bias[n])), zero pad cols N..NPout  (bf16, ldc)
template <int EPI>
__global__ __launch_bounds__(256) void gemm_bf(const short* __restrict__ A,
                                               const short* __restrict__ W,
                                               float* __restrict__ Cf,
                                               short* __restrict__ Cb,
                                               const float* __restrict__ res,
                                               const float* __restrict__ bias,
                                               const float* __restrict__ gamma,
                                               int M, int N, int KP, int ldc, int NPout) {
    __shared__ __align__(16) short As[128 * 64];
    __shared__ __align__(16) short Bs[128 * 64];

    const int tid = threadIdx.x;
    const int w = tid >> 6, l = tid & 63;
    const int wm = (w >> 1) * 64, wn = (w & 1) * 64;
    const int bm = blockIdx.y * 128, bn = blockIdx.x * 128;
    const int lrow = l >> 3, slot = l & 7;

    f32x4 acc[4][4] = {};

    for (int k0 = 0; k0 < KP; k0 += 64) {
        __syncthreads();
#pragma unroll
        for (int it = 0; it < 4; it++) {
            int row = it * 32 + w * 8 + lrow;
            int srcslot = slot ^ (row & 7);
            {
                const short* g = A + (size_t)(bm + row) * KP + k0 + srcslot * 8;
                gload_lds16(g, (char*)As + it * 4096 + w * 1024 + l * 16);
            }
            {
                const short* g = W + (size_t)(bn + row) * KP + k0 + srcslot * 8;
                gload_lds16(g, (char*)Bs + it * 4096 + w * 1024 + l * 16);
            }
        }
        __syncthreads();

#pragma unroll
        for (int kk = 0; kk < 2; kk++) {
            const int kbyte = kk * 64 + (l >> 4) * 16;
            bf16x8 af[4], bfr[4];
#pragma unroll
            for (int i = 0; i < 4; i++) {
                int r = wm + i * 16 + (l & 15);
                af[i] = *(const bf16x8*)((const char*)As + r * 128 + (kbyte ^ ((r & 7) << 4)));
            }
#pragma unroll
            for (int j = 0; j < 4; j++) {
                int r = wn + j * 16 + (l & 15);
                bfr[j] = *(const bf16x8*)((const char*)Bs + r * 128 + (kbyte ^ ((r & 7) << 4)));
            }
#pragma unroll
            for (int i = 0; i < 4; i++)
#pragma unroll
                for (int j = 0; j < 4; j++)
                    acc[i][j] = __builtin_amdgcn_mfma_f32_16x16x32_bf16(af[i], bfr[j], acc[i][j], 0, 0, 0);
        }
    }

    // epilogue: C/D layout col = lane&15, row = (lane>>4)*4 + reg
    const int col0 = bn + wn + (l & 15);
    const int rbase = (l >> 4) * 4;
#pragma unroll
    for (int i = 0; i < 4; i++) {
#pragma unroll
        for (int r = 0; r < 4; r++) {
            int gm = bm + wm + i * 16 + rbase + r;
            if (gm >= M) continue;
#pragma unroll
            for (int j = 0; j < 4; j++) {
                int gn = col0 + j * 16;
                float v = acc[i][j][r];
                if (EPI == 0) {
                    if (gn < N) Cf[(size_t)gm * ldc + gn] = v;
                } else if (EPI == 1) {
                    if (gn < N) Cf[(size_t)gm * ldc + gn] =
                        res[(size_t)gm * ldc + gn] + gamma[gn] * (v + bias[gn]);
                } else {
                    if (gn < NPout)
                        Cb[(size_t)gm * ldc + gn] = (gn < N) ? f2bf(gelu_exact(v + bias[gn])) : (short)0;
                }
            }
        }
    }
}

// ---------------- flash attention v2: Q in regs, P in regs, interleaved key ownership ----
// block (qt, hh, b), 256 threads: q = t>>2, sub = t&3; lane owns keys klocal = kk*4+sub.
// K/V staged in LDS [64][24] fp32 (stride 24 -> sub rows land in banks {0,24,16,8}: b128 conflict-free).
// Per-lane partial PV over own 16 keys x 20 dims; one cross-sub shfl reduce at the end.
__global__ __launch_bounds__(256) void attn_flash_kernel(const float* __restrict__ qkv,
                                                         const float* __restrict__ table,
                                                         const int* __restrict__ ridx,
                                                         short* __restrict__ ob) {
    __shared__ float Ks[64][24];
    __shared__ float Vs[64][24];

    const int qt = blockIdx.x;
    const int hh = blockIdx.y;
    const int b  = blockIdx.z;
    const int t  = threadIdx.x;
    const int q  = t >> 2;
    const int sub = t & 3;
    const int n  = qt * 64 + q;
    const bool qvalid = (n < 513);
    const float scale = 0.22360679774997896f;

    // Q in registers (pre-scaled)
    float qr[20];
    if (qvalid) {
        const float4* qp = (const float4*)(qkv + (b * 513 + n) * 600 + hh * 20);
#pragma unroll
        for (int i = 0; i < 5; i++) {
            float4 f = qp[i];
            qr[i * 4 + 0] = f.x * scale; qr[i * 4 + 1] = f.y * scale;
            qr[i * 4 + 2] = f.z * scale; qr[i * 4 + 3] = f.w * scale;
        }
    } else {
#pragma unroll
        for (int i = 0; i < 20; i++) qr[i] = 0.f;
    }

    float m = -1e30f;
    float lsum = 0.f;
    float acc[20] = {};
    const int krow_base = n * 513;

    for (int kt = 0; kt < 9; kt++) {
        __syncthreads();
        for (int l = t; l < 64 * 20; l += 256) {
            int kk = l / 20, i = l % 20;
            int gk = kt * 64 + kk;
            if (gk < 513) {
                const float* base = qkv + (b * 513 + gk) * 600 + hh * 20 + i;
                Ks[kk][i] = base[200];
                Vs[kk][i] = base[400];
            } else {
                Ks[kk][i] = 0.f;
                Vs[kk][i] = 0.f;
            }
        }
        __syncthreads();

        float sreg[16];
        float tm = -1e30f;
#pragma unroll
        for (int kk = 0; kk < 16; kk++) {
            const int klocal = kk * 4 + sub;
            const int gk = kt * 64 + klocal;
            float sv = -1e30f;
            if (qvalid && gk < 513) {
                sv = table[ridx[krow_base + gk] * 10 + hh];
                const float4* kr = (const float4*)&Ks[klocal][0];
#pragma unroll
                for (int i = 0; i < 5; i++) {
                    float4 kv = kr[i];
                    sv += qr[i * 4 + 0] * kv.x + qr[i * 4 + 1] * kv.y
                        + qr[i * 4 + 2] * kv.z + qr[i * 4 + 3] * kv.w;
                }
            }
            sreg[kk] = sv;
            tm = fmaxf(tm, sv);
        }
        tm = fmaxf(tm, __shfl_xor(tm, 1));
        tm = fmaxf(tm, __shfl_xor(tm, 2));
        float m_new = fmaxf(m, tm);
        float rescale = __expf(m - m_new);
        m = m_new;

        float ts = 0.f;
#pragma unroll
        for (int kk = 0; kk < 16; kk++) {
            float p = __expf(sreg[kk] - m_new);
            sreg[kk] = p;
            ts += p;
        }
        ts += __shfl_xor(ts, 1);
        ts += __shfl_xor(ts, 2);
        lsum = lsum * rescale + ts;
#pragma unroll
        for (int j = 0; j < 20; j++) acc[j] *= rescale;

#pragma unroll
        for (int kk = 0; kk < 16; kk++) {
            const int klocal = kk * 4 + sub;
            float p = sreg[kk];
            const float4* vr = (const float4*)&Vs[klocal][0];
#pragma unroll
            for (int i = 0; i < 5; i++) {
                float4 vv = vr[i];
                acc[i * 4 + 0] += p * vv.x; acc[i * 4 + 1] += p * vv.y;
                acc[i * 4 + 2] += p * vv.z; acc[i * 4 + 3] += p * vv.w;
            }
        }
    }

    // cross-sub reduce (lanes sub=0..3 hold partial sums over disjoint key sets)
#pragma unroll
    for (int j = 0; j < 20; j++) {
        acc[j] += __shfl_xor(acc[j], 1);
        acc[j] += __shfl_xor(acc[j], 2);
    }
    if (qvalid) {
        float inv = 1.f / lsum;
        const int d0 = sub * 5;
        short* op = ob + (size_t)(b * 513 + n) * 256 + hh * 20 + d0;
#pragma unroll
        for (int j = 0; j < 5; j++) op[j] = f2bf(acc[d0 + j] * inv);
    }
}

// ---------------- final: mean-pool patches -> LN -> head (200 -> 4) ----------------
__global__ __launch_bounds__(256) void final_kernel(const float* __restrict__ h,
                                                    const float* __restrict__ g,
                                                    const float* __restrict__ bb,
                                                    const float* __restrict__ hw,
                                                    const float* __restrict__ hb,
                                                    float* __restrict__ out) {
    __shared__ float pool[256];
    __shared__ float red[256];
    int b = blockIdx.x, t = threadIdx.x;
    float s = 0.f;
    if (t < 200) {
        const float* hp = h + b * 513 * 200 + 200 + t;
        for (int p = 0; p < 512; p++) s += hp[p * 200];
        s *= (1.f / 512.f);
    }
    pool[t] = (t < 200) ? s : 0.f;
    red[t] = pool[t];
    __syncthreads();
    for (int o = 128; o; o >>= 1) {
        if (t < o) red[t] += red[t + o];
        __syncthreads();
    }
    float mean = red[0] / 200.f;
    __syncthreads();
    float dv = (t < 200) ? (pool[t] - mean) : 0.f;
    red[t] = dv * dv;
    __syncthreads();
    for (int o = 128; o; o >>= 1) {
        if (t < o) red[t] += red[t + o];
        __syncthreads();
    }
    float var = red[0] / 200.f;
    float rstd = rsqrtf(var + 1e-6f);
    __syncthreads();
    if (t < 200) pool[t] = (pool[t] - mean) * rstd * g[t] + bb[t];
    __syncthreads();
    if (t < 4) {
        float acc = hb[t];
        for (int d2 = 0; d2 < 200; d2++) acc += pool[d2] * hw[t * 200 + d2];
        out[b * 4 + t] = acc;
    }
}

extern "C" void kernel_launch(void* const* d_in, const int* in_sizes, int n_in,
                              void* d_out, int out_size, void* d_ws, size_t ws_size,
                              hipStream_t stream) {
    const float* x        = (const float*)d_in[0];
    const float* conv1_w  = (const float*)d_in[1];
    const float* conv1_b  = (const float*)d_in[2];
    const float* gn1_g    = (const float*)d_in[3];
    const float* gn1_b    = (const float*)d_in[4];
    const float* conv2_w  = (const float*)d_in[5];
    const float* conv2_b  = (const float*)d_in[6];
    const float* gn2_g    = (const float*)d_in[7];
    const float* gn2_b    = (const float*)d_in[8];
    const float* conv3_w  = (const float*)d_in[9];
    const float* conv3_b  = (const float*)d_in[10];
    const float* gn3_g    = (const float*)d_in[11];
    const float* gn3_b    = (const float*)d_in[12];
    const float* cls_tok  = (const float*)d_in[13];
    const float* pos_emb  = (const float*)d_in[14];
    const float* time_emb = (const float*)d_in[15];
    const float* ln1_g    = (const float*)d_in[16];
    const float* ln1_b    = (const float*)d_in[17];
    const float* qkv_w    = (const float*)d_in[18];
    const float* rel_tab  = (const float*)d_in[19];
    const float* proj_w   = (const float*)d_in[20];
    const float* proj_b   = (const float*)d_in[21];
    const float* gamma1   = (const float*)d_in[22];
    const float* ln2_g    = (const float*)d_in[23];
    const float* ln2_b    = (const float*)d_in[24];
    const float* fc1_w    = (const float*)d_in[25];
    const float* fc1_b    = (const float*)d_in[26];
    const float* fc2_w    = (const float*)d_in[27];
    const float* fc2_b    = (const float*)d_in[28];
    const float* gamma2   = (const float*)d_in[29];
    const float* fcn_g    = (const float*)d_in[30];
    const float* fcn_b    = (const float*)d_in[31];
    const float* head_w   = (const float*)d_in[32];
    const float* head_b   = (const float*)d_in[33];
    const int*   rel_idx  = (const int*)d_in[34];

    // ---- workspace layout (bytes). total ~31.2 MB ----
    char* wsb = (char*)d_ws;
    float* h    = (float*)wsb;                      // 8*513*200 f32      = 3,283,200 B
    char* p = wsb + 3283200;
    float* qkvb = (float*)p;                        // 4104*600 f32       = 9,849,600 B
    short* mlp  = (short*)p;                        //   alias: 4104*832 bf16 = 6,829,056 B
    float* c1   = (float*)p;                        //   alias: conv scratch
    float* c2   = c1 + 819200;
    p += 9849600;
    short* y    = (short*)p; p += 2101248;          // 4104*256 bf16
    short* ob   = (short*)p; p += 2101248;          // 4104*256 bf16
    short* wqkv = (short*)p; p += 3686400;          // 12*600*256 bf16
    short* wproj= (short*)p; p += 1228800;          // 12*200*256 bf16
    short* wfc1 = (short*)p; p += 4915200;          // 12*800*256 bf16
    short* wfc2 = (short*)p; p += 3993600;          // 12*200*832 bf16
    float* stats= (float*)p;                        // 256 B

    // ---- weight convert+pad (once per call) ----
    convpad_kernel<<<(7200 * 256 + 255) / 256, 256, 0, stream>>>(qkv_w, wqkv, 7200, 200, 256);
    convpad_kernel<<<(2400 * 256 + 255) / 256, 256, 0, stream>>>(proj_w, wproj, 2400, 200, 256);
    convpad_kernel<<<(9600 * 256 + 255) / 256, 256, 0, stream>>>(fc1_w, wfc1, 9600, 200, 256);
    convpad_kernel<<<(2400 * 832 + 255) / 256, 256, 0, stream>>>(fc2_w, wfc2, 2400, 800, 832);
    hipMemsetAsync(ob, 0, 2101248, stream);  // zero pad cols of ob once per call

    // ---- patch embed ----
    conv1_kernel<<<3200, 256, 0, stream>>>(x, conv1_w, conv1_b, c1);
    gn_stats_kernel<<<32, 256, 0, stream>>>(c1, stats);
    gn_apply_kernel<<<3200, 256, 0, stream>>>(c1, stats, gn1_g, gn1_b);
    conv3x1_kernel<<<3200, 256, 0, stream>>>(c1, conv2_w, conv2_b, c2);
    gn_stats_kernel<<<32, 256, 0, stream>>>(c2, stats);
    gn_apply_kernel<<<3200, 256, 0, stream>>>(c2, stats, gn2_g, gn2_b);
    conv3x1_kernel<<<3200, 256, 0, stream>>>(c2, conv3_w, conv3_b, c1);
    gn_stats_kernel<<<32, 256, 0, stream>>>(c1, stats);
    gn_apply_kernel<<<3200, 256, 0, stream>>>(c1, stats, gn3_g, gn3_b);
    embed_kernel<<<(820800 + 255) / 256, 256, 0, stream>>>(c1, cls_tok, pos_emb, time_emb, h);

    // ---- transformer layers ----
    for (int d = 0; d < 12; d++) {
        ln_kernel<<<4104, 64, 0, stream>>>(h, ln1_g + d * 200, ln1_b + d * 200, y);
        gemm_bf<0><<<dim3(5, 33), 256, 0, stream>>>(y, wqkv + d * 153600, qkvb, nullptr,
                                                    nullptr, nullptr, nullptr,
                                                    4104, 600, 256, 600, 0);
        attn_flash_kernel<<<dim3(9, 10, 8), 256, 0, stream>>>(qkvb, rel_tab + d * 19080, rel_idx, ob);
        gemm_bf<1><<<dim3(2, 33), 256, 0, stream>>>(ob, wproj + d * 51200, h, nullptr,
                                                    h, proj_b + d * 200, gamma1 + d * 200,
                                                    4104, 200, 256, 200, 0);
        ln_kernel<<<4104, 64, 0, stream>>>(h, ln2_g + d * 200, ln2_b + d * 200, y);
        gemm_bf<2><<<dim3(7, 33), 256, 0, stream>>>(y, wfc1 + d * 204800, nullptr, mlp,
                                                    nullptr, fc1_b + d * 800, nullptr,
                                                    4104, 800, 256, 832, 832);
        gemm_bf<1><<<dim3(2, 33), 256, 0, stream>>>(mlp, wfc2 + d * 166400, h, nullptr,
                                                    h, fc2_b + d * 200, gamma2 + d * 200,
                                                    4104, 200, 832, 200, 0);
    }

    // ---- pool + head ----
    final_kernel<<<8, 256, 0, stream>>>(h, fcn_g, fcn_b, head_w, head_b, (float*)d_out);
}

// Round 5
// 2137.730 us; speedup vs baseline: 3.1967x; 1.1709x over previous
//
#include <hip/hip_runtime.h>
#include <math.h>

#define DEV static __device__ __forceinline__

typedef __attribute__((ext_vector_type(8))) short bf16x8;
typedef __attribute__((ext_vector_type(4))) float f32x4;

DEV float gelu_exact(float x) {
    return 0.5f * x * (1.0f + erff(x * 0.70710678118654752f));
}

DEV short f2bf(float f) {
    union { float f; unsigned u; } v; v.f = f;
    unsigned r = v.u + 0x7FFF + ((v.u >> 16) & 1);  // round-to-nearest-even
    return (short)(r >> 16);
}

DEV float bf2f(unsigned short b) {
    union { unsigned u; float f; } v; v.u = ((unsigned)b) << 16;
    return v.f;
}

DEV unsigned pack2bf(float a, float b) {
    return ((unsigned)(unsigned short)f2bf(a)) | (((unsigned)(unsigned short)f2bf(b)) << 16);
}

DEV void gload_lds16(const void* g, void* lds) {
    __builtin_amdgcn_global_load_lds(
        (const __attribute__((address_space(1))) void*)g,
        (__attribute__((address_space(3))) void*)lds, 16, 0, 0);
}

// ---------------- conv1: (B,1,512,200) -> (B,8,512,25), k=15 stride=8 pad=7 ----------------
__global__ void conv1_kernel(const float* __restrict__ x, const float* __restrict__ w,
                             const float* __restrict__ bias, float* __restrict__ out) {
    int idx = blockIdx.x * blockDim.x + threadIdx.x;
    const int total = 8 * 8 * 512 * 25;
    if (idx >= total) return;
    int ow = idx % 25;
    int p  = (idx / 25) % 512;
    int oc = (idx / (25 * 512)) % 8;
    int b  = idx / (25 * 512 * 8);
    const float* xp = x + b * 512 * 200 + p * 200;
    const float* wp = w + oc * 15;
    float acc = bias[oc];
    int t0 = ow * 8 - 7;
#pragma unroll
    for (int k = 0; k < 15; k++) {
        int t = t0 + k;
        if (t >= 0 && t < 200) acc += wp[k] * xp[t];
    }
    out[idx] = acc;
}

// ---------------- conv 1x3 (pad 1) on (B,8,512,25) ----------------
__global__ void conv3x1_kernel(const float* __restrict__ in, const float* __restrict__ w,
                               const float* __restrict__ bias, float* __restrict__ out) {
    int idx = blockIdx.x * blockDim.x + threadIdx.x;
    const int total = 8 * 8 * 512 * 25;
    if (idx >= total) return;
    int ow = idx % 25;
    int p  = (idx / 25) % 512;
    int oc = (idx / 12800) & 7;
    int b  = idx / 102400;
    float acc = bias[oc];
#pragma unroll
    for (int ic = 0; ic < 8; ic++) {
        const float* ip = in + b * 102400 + ic * 12800 + p * 25;
        const float* wp = w + oc * 24 + ic * 3;
        if (ow > 0)  acc += wp[0] * ip[ow - 1];
        acc += wp[1] * ip[ow];
        if (ow < 24) acc += wp[2] * ip[ow + 1];
    }
    out[idx] = acc;
}

// ---------------- groupnorm stats ----------------
__global__ void gn_stats_kernel(const float* __restrict__ buf, float* __restrict__ stats) {
    int b = blockIdx.x >> 2, g = blockIdx.x & 3;
    const float* base = buf + b * 102400 + g * 2 * 12800;
    float s = 0.f, s2 = 0.f;
    for (int l = threadIdx.x; l < 25600; l += 256) {
        float v = base[l];
        s += v; s2 += v * v;
    }
    __shared__ float ss[256], ss2[256];
    ss[threadIdx.x] = s; ss2[threadIdx.x] = s2;
    __syncthreads();
    for (int o = 128; o; o >>= 1) {
        if (threadIdx.x < o) { ss[threadIdx.x] += ss[threadIdx.x + o]; ss2[threadIdx.x] += ss2[threadIdx.x + o]; }
        __syncthreads();
    }
    if (threadIdx.x == 0) {
        float m = ss[0] / 25600.f;
        float v = ss2[0] / 25600.f - m * m;
        stats[blockIdx.x * 2] = m;
        stats[blockIdx.x * 2 + 1] = v;
    }
}

__global__ void gn_apply_kernel(float* __restrict__ buf, const float* __restrict__ stats,
                                const float* __restrict__ g, const float* __restrict__ bb) {
    int idx = blockIdx.x * blockDim.x + threadIdx.x;
    if (idx >= 8 * 102400) return;
    int c = (idx / 12800) & 7;
    int b = idx / 102400;
    int grp = c >> 1;
    float m = stats[(b * 4 + grp) * 2];
    float v = stats[(b * 4 + grp) * 2 + 1];
    float val = (buf[idx] - m) * rsqrtf(v + 1e-5f) * g[c] + bb[c];
    buf[idx] = gelu_exact(val);
}

// ---------------- embed ----------------
__global__ void embed_kernel(const float* __restrict__ conv, const float* __restrict__ cls,
                             const float* __restrict__ pos, const float* __restrict__ te,
                             float* __restrict__ h) {
    int idx = blockIdx.x * blockDim.x + threadIdx.x;
    if (idx >= 8 * 513 * 200) return;
    int d = idx % 200;
    int n = (idx / 200) % 513;
    int b = idx / (200 * 513);
    float val;
    if (n == 0) {
        val = cls[d] + pos[d];
    } else {
        int p = n - 1;
        int t = d >> 3;
        int c = d & 7;
        val = conv[b * 102400 + c * 12800 + p * 25 + t];
        int ch = p >> 3, tw = p & 7;
        val += pos[(1 + ch) * 200 + d] + te[tw * 200 + d];
    }
    h[idx] = val;
}

// ---------------- weight convert+pad: fp32 [R][K] -> bf16 [R][KP] (zero pad) ----------------
__global__ void convpad_kernel(const float* __restrict__ src, short* __restrict__ dst,
                               int R, int K, int KP) {
    int idx = blockIdx.x * blockDim.x + threadIdx.x;
    if (idx >= R * KP) return;
    int r = idx / KP, c = idx % KP;
    dst[idx] = (c < K) ? f2bf(src[r * K + c]) : (short)0;
}

// ---------------- bias precompute: bias[h][q][516] bf16 = table[ridx[q][k]*10+h] ----------
__global__ void bias_pre_kernel(const float* __restrict__ table, const int* __restrict__ ridx,
                                short* __restrict__ bias) {
    int idx = blockIdx.x * blockDim.x + threadIdx.x;
    if (idx >= 10 * 513 * 129) return;
    int j = idx % 129;
    int q = (idx / 129) % 513;
    int h = idx / (129 * 513);
    int k0 = j * 4;
    int k1 = min(k0 + 1, 512), k2 = min(k0 + 2, 512), k3 = min(k0 + 3, 512);
    const int* rp = ridx + q * 513;
    float b0 = table[rp[k0] * 10 + h];
    float b1 = table[rp[k1] * 10 + h];
    float b2 = table[rp[k2] * 10 + h];
    float b3 = table[rp[k3] * 10 + h];
    uint2 pk;
    pk.x = pack2bf(b0, b1);
    pk.y = pack2bf(b2, b3);
    *(uint2*)&bias[((size_t)h * 513 + q) * 516 + k0] = pk;
}

// ---------------- LayerNorm over D=200, one wave per row; bf16 [row][256] out ----------------
__global__ __launch_bounds__(64) void ln_kernel(const float* __restrict__ in,
                                                const float* __restrict__ g,
                                                const float* __restrict__ b,
                                                short* __restrict__ out) {
    int row = blockIdx.x;
    int lane = threadIdx.x;
    const float* x = in + row * 200;
    float v[4];
    float s = 0.f;
#pragma unroll
    for (int i = 0; i < 4; i++) {
        int d = lane + i * 64;
        v[i] = (d < 200) ? x[d] : 0.f;
        s += v[i];
    }
#pragma unroll
    for (int o = 32; o; o >>= 1) s += __shfl_xor(s, o);
    float mean = s * (1.f / 200.f);
    float s2 = 0.f;
#pragma unroll
    for (int i = 0; i < 4; i++) {
        int d = lane + i * 64;
        float dv = (d < 200) ? (v[i] - mean) : 0.f;
        s2 += dv * dv;
    }
#pragma unroll
    for (int o = 32; o; o >>= 1) s2 += __shfl_xor(s2, o);
    float rstd = rsqrtf(s2 * (1.f / 200.f) + 1e-6f);
#pragma unroll
    for (int i = 0; i < 4; i++) {
        int d = lane + i * 64;
        float val = (d < 200) ? (v[i] - mean) * rstd * g[d] + b[d] : 0.f;
        out[row * 256 + d] = f2bf(val);
    }
}

// ---------------- bf16 MFMA GEMM: C[M,N] = A[M,KP] @ W[N,KP]^T (+ epilogue) ----------------
template <int EPI>
__global__ __launch_bounds__(256) void gemm_bf(const short* __restrict__ A,
                                               const short* __restrict__ W,
                                               float* __restrict__ Cf,
                                               short* __restrict__ Cb,
                                               const float* __restrict__ res,
                                               const float* __restrict__ bias,
                                               const float* __restrict__ gamma,
                                               int M, int N, int KP, int ldc, int NPout) {
    __shared__ __align__(16) short As[128 * 64];
    __shared__ __align__(16) short Bs[128 * 64];

    const int tid = threadIdx.x;
    const int w = tid >> 6, l = tid & 63;
    const int wm = (w >> 1) * 64, wn = (w & 1) * 64;
    const int bm = blockIdx.y * 128, bn = blockIdx.x * 128;
    const int lrow = l >> 3, slot = l & 7;

    f32x4 acc[4][4] = {};

    for (int k0 = 0; k0 < KP; k0 += 64) {
        __syncthreads();
#pragma unroll
        for (int it = 0; it < 4; it++) {
            int row = it * 32 + w * 8 + lrow;
            int srcslot = slot ^ (row & 7);
            {
                const short* g = A + (size_t)(bm + row) * KP + k0 + srcslot * 8;
                gload_lds16(g, (char*)As + it * 4096 + w * 1024 + l * 16);
            }
            {
                const short* g = W + (size_t)(bn + row) * KP + k0 + srcslot * 8;
                gload_lds16(g, (char*)Bs + it * 4096 + w * 1024 + l * 16);
            }
        }
        __syncthreads();

#pragma unroll
        for (int kk = 0; kk < 2; kk++) {
            const int kbyte = kk * 64 + (l >> 4) * 16;
            bf16x8 af[4], bfr[4];
#pragma unroll
            for (int i = 0; i < 4; i++) {
                int r = wm + i * 16 + (l & 15);
                af[i] = *(const bf16x8*)((const char*)As + r * 128 + (kbyte ^ ((r & 7) << 4)));
            }
#pragma unroll
            for (int j = 0; j < 4; j++) {
                int r = wn + j * 16 + (l & 15);
                bfr[j] = *(const bf16x8*)((const char*)Bs + r * 128 + (kbyte ^ ((r & 7) << 4)));
            }
#pragma unroll
            for (int i = 0; i < 4; i++)
#pragma unroll
                for (int j = 0; j < 4; j++)
                    acc[i][j] = __builtin_amdgcn_mfma_f32_16x16x32_bf16(af[i], bfr[j], acc[i][j], 0, 0, 0);
        }
    }

    const int col0 = bn + wn + (l & 15);
    const int rbase = (l >> 4) * 4;
#pragma unroll
    for (int i = 0; i < 4; i++) {
#pragma unroll
        for (int r = 0; r < 4; r++) {
            int gm = bm + wm + i * 16 + rbase + r;
            if (gm >= M) continue;
#pragma unroll
            for (int j = 0; j < 4; j++) {
                int gn = col0 + j * 16;
                float v = acc[i][j][r];
                if (EPI == 0) {
                    if (gn < N) Cf[(size_t)gm * ldc + gn] = v;
                } else if (EPI == 1) {
                    if (gn < N) Cf[(size_t)gm * ldc + gn] =
                        res[(size_t)gm * ldc + gn] + gamma[gn] * (v + bias[gn]);
                } else {
                    if (gn < NPout)
                        Cb[(size_t)gm * ldc + gn] = (gn < N) ? f2bf(gelu_exact(v + bias[gn])) : (short)0;
                }
            }
        }
    }
}

// ---------------- MFMA flash attention ----------------
// Block (qt 0..8, h 0..9, b 0..7), 256 threads = 4 waves x 16 queries.
// S^T = K.Q^T via mfma(A=K rows, B=Q rows) -> C[key][q]: lane owns ONE query (col l&15).
// Softmax lane-local + shfl_xor(16,32). P packed bf16 to per-wave LDS.
// O^T = V^T.P^T via mfma(A=Vt rows, B=P rows), acc in C/D layout, scalar rescale per lane.
__global__ __launch_bounds__(256) void attn_mfma_kernel(const float* __restrict__ qkv,
                                                        const short* __restrict__ bias,
                                                        short* __restrict__ ob) {
    __shared__ __align__(16) short Kb[64 * 24 + 8];  // [key][24], cols 20..23 zero, tail zero
    __shared__ __align__(16) short Vt[32 * 80];      // [d][80] keys at cols 0..63, rows 20..31 zero
    __shared__ __align__(16) short Pl[4 * 16 * 80];  // per-wave [q][80]

    const int qt = blockIdx.x, hh = blockIdx.y, b = blockIdx.z;
    const int t = threadIdx.x, wave = t >> 6, l = t & 63;
    const int lq = l & 15, hi = l >> 4;
    const int n = qt * 64 + wave * 16 + lq;
    const int nc = min(n, 512);
    const float scale = 0.22360679774997896f;  // 1/sqrt(20)

    if (t < 8) Kb[1536 + t] = 0;

    // Q B-fragment in registers: 8 bf16 = head-dims hi*8..hi*8+7, zero for hd>=20
    bf16x8 qf;
    {
        const float* qp = qkv + (size_t)(b * 513 + nc) * 600 + hh * 20;
#pragma unroll
        for (int e = 0; e < 8; e++) {
            int hd = hi * 8 + e;
            qf[e] = (hd < 20) ? f2bf(qp[hd] * scale) : (short)0;
        }
    }

    float mrun = -1e30f, lsum = 0.f;
    f32x4 oacc0 = {}, oacc1 = {};
    const f32x4 zero4 = {};
    const size_t brow = ((size_t)hh * 513 + nc) * 516;

    for (int kt = 0; kt < 9; kt++) {
        __syncthreads();
        // stage K [64][24] bf16 (cols >=20 and keys >=513 -> 0)
#pragma unroll
        for (int it = 0; it < 6; it++) {
            int idx2 = t + it * 256;
            int key = idx2 / 24, i = idx2 % 24;
            int gk = kt * 64 + key;
            float v = (i < 20 && gk < 513) ? qkv[(size_t)(b * 513 + gk) * 600 + 200 + hh * 20 + i] : 0.f;
            Kb[key * 24 + i] = f2bf(v);
        }
        // stage V transposed [32][80] (rows >=20 and keys >=513 -> 0)
#pragma unroll
        for (int it = 0; it < 8; it++) {
            int idx2 = t + it * 256;
            int key = idx2 >> 5, i = idx2 & 31;
            int gk = kt * 64 + key;
            float v = (i < 20 && gk < 513) ? qkv[(size_t)(b * 513 + gk) * 600 + 400 + hh * 20 + i] : 0.f;
            Vt[i * 80 + key] = f2bf(v);
        }
        __syncthreads();

        // S^T: 4 mfma over 16-key chunks
        f32x4 s[4];
#pragma unroll
        for (int c = 0; c < 4; c++) {
            bf16x8 kf = *(const bf16x8*)&Kb[(c * 16 + lq) * 24 + hi * 8];
            s[c] = __builtin_amdgcn_mfma_f32_16x16x32_bf16(kf, qf, zero4, 0, 0, 0);
        }

        // bias add + key mask + row stats
        float sv[4][4];
        float tm = -1e30f;
#pragma unroll
        for (int c = 0; c < 4; c++) {
            int kglob = kt * 64 + c * 16 + hi * 4;
            uint2 bl = *(const uint2*)&bias[brow + min(kglob, 512)];
            float bv[4] = { bf2f((unsigned short)(bl.x & 0xFFFF)), bf2f((unsigned short)(bl.x >> 16)),
                            bf2f((unsigned short)(bl.y & 0xFFFF)), bf2f((unsigned short)(bl.y >> 16)) };
#pragma unroll
            for (int r = 0; r < 4; r++) {
                float val = s[c][r] + bv[r];
                if (kglob + r > 512) val = -1e30f;
                sv[c][r] = val;
                tm = fmaxf(tm, val);
            }
        }
        tm = fmaxf(tm, __shfl_xor(tm, 16));
        tm = fmaxf(tm, __shfl_xor(tm, 32));
        float mnew = fmaxf(mrun, tm);
        float resc = __expf(mrun - mnew);
        mrun = mnew;

        float ts = 0.f;
#pragma unroll
        for (int c = 0; c < 4; c++) {
            float p0 = __expf(sv[c][0] - mnew);
            float p1 = __expf(sv[c][1] - mnew);
            float p2 = __expf(sv[c][2] - mnew);
            float p3 = __expf(sv[c][3] - mnew);
            ts += (p0 + p1) + (p2 + p3);
            uint2 pk;
            pk.x = pack2bf(p0, p1);
            pk.y = pack2bf(p2, p3);
            *(uint2*)&Pl[wave * 1280 + lq * 80 + c * 16 + hi * 4] = pk;
        }
        ts += __shfl_xor(ts, 16);
        ts += __shfl_xor(ts, 32);
        lsum = lsum * resc + ts;
        oacc0 *= resc;
        oacc1 *= resc;

        // PV: O^T += V^T . P^T   (per-wave Pl, wave-internal ordering via compiler waitcnts)
#pragma unroll
        for (int kc = 0; kc < 2; kc++) {
            bf16x8 pf = *(const bf16x8*)&Pl[wave * 1280 + lq * 80 + kc * 32 + hi * 8];
            bf16x8 vf0 = *(const bf16x8*)&Vt[lq * 80 + kc * 32 + hi * 8];
            bf16x8 vf1 = *(const bf16x8*)&Vt[(16 + lq) * 80 + kc * 32 + hi * 8];
            oacc0 = __builtin_amdgcn_mfma_f32_16x16x32_bf16(vf0, pf, oacc0, 0, 0, 0);
            oacc1 = __builtin_amdgcn_mfma_f32_16x16x32_bf16(vf1, pf, oacc1, 0, 0, 0);
        }
    }

    if (n < 513) {
        float inv = 1.f / lsum;
        short* op = ob + (size_t)(b * 513 + n) * 256 + hh * 20;
        {
            int d0 = hi * 4;  // 0,4,8,12
            uint2 pk;
            pk.x = pack2bf(oacc0[0] * inv, oacc0[1] * inv);
            pk.y = pack2bf(oacc0[2] * inv, oacc0[3] * inv);
            *(uint2*)&op[d0] = pk;
        }
        if (hi == 0) {  // d = 16..19
            uint2 pk;
            pk.x = pack2bf(oacc1[0] * inv, oacc1[1] * inv);
            pk.y = pack2bf(oacc1[2] * inv, oacc1[3] * inv);
            *(uint2*)&op[16] = pk;
        }
    }
}

// ---------------- final: mean-pool patches -> LN -> head (200 -> 4) ----------------
__global__ __launch_bounds__(256) void final_kernel(const float* __restrict__ h,
                                                    const float* __restrict__ g,
                                                    const float* __restrict__ bb,
                                                    const float* __restrict__ hw,
                                                    const float* __restrict__ hb,
                                                    float* __restrict__ out) {
    __shared__ float pool[256];
    __shared__ float red[256];
    int b = blockIdx.x, t = threadIdx.x;
    float s = 0.f;
    if (t < 200) {
        const float* hp = h + b * 513 * 200 + 200 + t;
        for (int p = 0; p < 512; p++) s += hp[p * 200];
        s *= (1.f / 512.f);
    }
    pool[t] = (t < 200) ? s : 0.f;
    red[t] = pool[t];
    __syncthreads();
    for (int o = 128; o; o >>= 1) {
        if (t < o) red[t] += red[t + o];
        __syncthreads();
    }
    float mean = red[0] / 200.f;
    __syncthreads();
    float dv = (t < 200) ? (pool[t] - mean) : 0.f;
    red[t] = dv * dv;
    __syncthreads();
    for (int o = 128; o; o >>= 1) {
        if (t < o) red[t] += red[t + o];
        __syncthreads();
    }
    float var = red[0] / 200.f;
    float rstd = rsqrtf(var + 1e-6f);
    __syncthreads();
    if (t < 200) pool[t] = (pool[t] - mean) * rstd * g[t] + bb[t];
    __syncthreads();
    if (t < 4) {
        float acc = hb[t];
        for (int d2 = 0; d2 < 200; d2++) acc += pool[d2] * hw[t * 200 + d2];
        out[b * 4 + t] = acc;
    }
}

extern "C" void kernel_launch(void* const* d_in, const int* in_sizes, int n_in,
                              void* d_out, int out_size, void* d_ws, size_t ws_size,
                              hipStream_t stream) {
    const float* x        = (const float*)d_in[0];
    const float* conv1_w  = (const float*)d_in[1];
    const float* conv1_b  = (const float*)d_in[2];
    const float* gn1_g    = (const float*)d_in[3];
    const float* gn1_b    = (const float*)d_in[4];
    const float* conv2_w  = (const float*)d_in[5];
    const float* conv2_b  = (const float*)d_in[6];
    const float* gn2_g    = (const float*)d_in[7];
    const float* gn2_b    = (const float*)d_in[8];
    const float* conv3_w  = (const float*)d_in[9];
    const float* conv3_b  = (const float*)d_in[10];
    const float* gn3_g    = (const float*)d_in[11];
    const float* gn3_b    = (const float*)d_in[12];
    const float* cls_tok  = (const float*)d_in[13];
    const float* pos_emb  = (const float*)d_in[14];
    const float* time_emb = (const float*)d_in[15];
    const float* ln1_g    = (const float*)d_in[16];
    const float* ln1_b    = (const float*)d_in[17];
    const float* qkv_w    = (const float*)d_in[18];
    const float* rel_tab  = (const float*)d_in[19];
    const float* proj_w   = (const float*)d_in[20];
    const float* proj_b   = (const float*)d_in[21];
    const float* gamma1   = (const float*)d_in[22];
    const float* ln2_g    = (const float*)d_in[23];
    const float* ln2_b    = (const float*)d_in[24];
    const float* fc1_w    = (const float*)d_in[25];
    const float* fc1_b    = (const float*)d_in[26];
    const float* fc2_w    = (const float*)d_in[27];
    const float* fc2_b    = (const float*)d_in[28];
    const float* gamma2   = (const float*)d_in[29];
    const float* fcn_g    = (const float*)d_in[30];
    const float* fcn_b    = (const float*)d_in[31];
    const float* head_w   = (const float*)d_in[32];
    const float* head_b   = (const float*)d_in[33];
    const int*   rel_idx  = (const int*)d_in[34];

    // ---- workspace layout (bytes), total ~36.5 MB ----
    char* p = (char*)d_ws;
    float* h    = (float*)p; p += 3283200;          // 8*513*200 f32
    float* qkvb = (float*)p;                        // 4104*600 f32
    short* mlp  = (short*)p;                        //   alias: 4104*832 bf16
    float* c1   = (float*)p;                        //   alias: conv scratch
    float* c2   = c1 + 819200;
    p += 9849600;
    short* y    = (short*)p; p += 2101248;          // 4104*256 bf16
    short* ob   = (short*)p; p += 2101248;          // 4104*256 bf16
    short* wqkv = (short*)p; p += 3686400;          // 12*600*256 bf16
    short* wproj= (short*)p; p += 1228800;          // 12*200*256 bf16
    short* wfc1 = (short*)p; p += 4915200;          // 12*800*256 bf16
    short* wfc2 = (short*)p; p += 3993600;          // 12*200*832 bf16
    short* biasb= (short*)p; p += 5294160;          // 10*513*516 bf16
    float* stats= (float*)p;                        // 256 B

    // ---- weight convert+pad (once per call) ----
    convpad_kernel<<<(7200 * 256 + 255) / 256, 256, 0, stream>>>(qkv_w, wqkv, 7200, 200, 256);
    convpad_kernel<<<(2400 * 256 + 255) / 256, 256, 0, stream>>>(proj_w, wproj, 2400, 200, 256);
    convpad_kernel<<<(9600 * 256 + 255) / 256, 256, 0, stream>>>(fc1_w, wfc1, 9600, 200, 256);
    convpad_kernel<<<(2400 * 832 + 255) / 256, 256, 0, stream>>>(fc2_w, wfc2, 2400, 800, 832);
    hipMemsetAsync(ob, 0, 2101248, stream);  // zero pad cols of ob once per call

    // ---- patch embed ----
    conv1_kernel<<<3200, 256, 0, stream>>>(x, conv1_w, conv1_b, c1);
    gn_stats_kernel<<<32, 256, 0, stream>>>(c1, stats);
    gn_apply_kernel<<<3200, 256, 0, stream>>>(c1, stats, gn1_g, gn1_b);
    conv3x1_kernel<<<3200, 256, 0, stream>>>(c1, conv2_w, conv2_b, c2);
    gn_stats_kernel<<<32, 256, 0, stream>>>(c2, stats);
    gn_apply_kernel<<<3200, 256, 0, stream>>>(c2, stats, gn2_g, gn2_b);
    conv3x1_kernel<<<3200, 256, 0, stream>>>(c2, conv3_w, conv3_b, c1);
    gn_stats_kernel<<<32, 256, 0, stream>>>(c1, stats);
    gn_apply_kernel<<<3200, 256, 0, stream>>>(c1, stats, gn3_g, gn3_b);
    embed_kernel<<<(820800 + 255) / 256, 256, 0, stream>>>(c1, cls_tok, pos_emb, time_emb, h);

    // ---- transformer layers ----
    for (int d = 0; d < 12; d++) {
        ln_kernel<<<4104, 64, 0, stream>>>(h, ln1_g + d * 200, ln1_b + d * 200, y);
        gemm_bf<0><<<dim3(5, 33), 256, 0, stream>>>(y, wqkv + d * 153600, qkvb, nullptr,
                                                    nullptr, nullptr, nullptr,
                                                    4104, 600, 256, 600, 0);
        bias_pre_kernel<<<(10 * 513 * 129 + 255) / 256, 256, 0, stream>>>(rel_tab + d * 19080, rel_idx, biasb);
        attn_mfma_kernel<<<dim3(9, 10, 8), 256, 0, stream>>>(qkvb, biasb, ob);
        gemm_bf<1><<<dim3(2, 33), 256, 0, stream>>>(ob, wproj + d * 51200, h, nullptr,
                                                    h, proj_b + d * 200, gamma1 + d * 200,
                                                    4104, 200, 256, 200, 0);
        ln_kernel<<<4104, 64, 0, stream>>>(h, ln2_g + d * 200, ln2_b + d * 200, y);
        gemm_bf<2><<<dim3(7, 33), 256, 0, stream>>>(y, wfc1 + d * 204800, nullptr, mlp,
                                                    nullptr, fc1_b + d * 800, nullptr,
                                                    4104, 800, 256, 832, 832);
        gemm_bf<1><<<dim3(2, 33), 256, 0, stream>>>(mlp, wfc2 + d * 166400, h, nullptr,
                                                    h, fc2_b + d * 200, gamma2 + d * 200,
                                                    4104, 200, 832, 200, 0);
    }

    // ---- pool + head ----
    final_kernel<<<8, 256, 0, stream>>>(h, fcn_g, fcn_b, head_w, head_b, (float*)d_out);
}

// Round 6
// 1289.334 us; speedup vs baseline: 5.3002x; 1.6580x over previous
//
#include <hip/hip_runtime.h>
#include <math.h>

#define DEV static __device__ __forceinline__

typedef __attribute__((ext_vector_type(8))) short bf16x8;
typedef __attribute__((ext_vector_type(4))) float f32x4;

DEV float gelu_exact(float x) {
    return 0.5f * x * (1.0f + erff(x * 0.70710678118654752f));
}

DEV short f2bf(float f) {
    union { float f; unsigned u; } v; v.f = f;
    unsigned r = v.u + 0x7FFF + ((v.u >> 16) & 1);  // round-to-nearest-even
    return (short)(r >> 16);
}

DEV float bf2f(unsigned short b) {
    union { unsigned u; float f; } v; v.u = ((unsigned)b) << 16;
    return v.f;
}

DEV unsigned pack2bf(float a, float b) {
    return ((unsigned)(unsigned short)f2bf(a)) | (((unsigned)(unsigned short)f2bf(b)) << 16);
}

DEV void gload_lds16(const void* g, void* lds) {
    __builtin_amdgcn_global_load_lds(
        (const __attribute__((address_space(1))) void*)g,
        (__attribute__((address_space(3))) void*)lds, 16, 0, 0);
}

// ---------------- conv1: (B,1,512,200) -> (B,8,512,25), k=15 stride=8 pad=7 ----------------
__global__ void conv1_kernel(const float* __restrict__ x, const float* __restrict__ w,
                             const float* __restrict__ bias, float* __restrict__ out) {
    int idx = blockIdx.x * blockDim.x + threadIdx.x;
    const int total = 8 * 8 * 512 * 25;
    if (idx >= total) return;
    int ow = idx % 25;
    int p  = (idx / 25) % 512;
    int oc = (idx / (25 * 512)) % 8;
    int b  = idx / (25 * 512 * 8);
    const float* xp = x + b * 512 * 200 + p * 200;
    const float* wp = w + oc * 15;
    float acc = bias[oc];
    int t0 = ow * 8 - 7;
#pragma unroll
    for (int k = 0; k < 15; k++) {
        int t = t0 + k;
        if (t >= 0 && t < 200) acc += wp[k] * xp[t];
    }
    out[idx] = acc;
}

// ---------------- conv 1x3 (pad 1) on (B,8,512,25) ----------------
__global__ void conv3x1_kernel(const float* __restrict__ in, const float* __restrict__ w,
                               const float* __restrict__ bias, float* __restrict__ out) {
    int idx = blockIdx.x * blockDim.x + threadIdx.x;
    const int total = 8 * 8 * 512 * 25;
    if (idx >= total) return;
    int ow = idx % 25;
    int p  = (idx / 25) % 512;
    int oc = (idx / 12800) & 7;
    int b  = idx / 102400;
    float acc = bias[oc];
#pragma unroll
    for (int ic = 0; ic < 8; ic++) {
        const float* ip = in + b * 102400 + ic * 12800 + p * 25;
        const float* wp = w + oc * 24 + ic * 3;
        if (ow > 0)  acc += wp[0] * ip[ow - 1];
        acc += wp[1] * ip[ow];
        if (ow < 24) acc += wp[2] * ip[ow + 1];
    }
    out[idx] = acc;
}

// ---------------- groupnorm ----------------
__global__ void gn_stats_kernel(const float* __restrict__ buf, float* __restrict__ stats) {
    int b = blockIdx.x >> 2, g = blockIdx.x & 3;
    const float* base = buf + b * 102400 + g * 2 * 12800;
    float s = 0.f, s2 = 0.f;
    for (int l = threadIdx.x; l < 25600; l += 256) {
        float v = base[l];
        s += v; s2 += v * v;
    }
    __shared__ float ss[256], ss2[256];
    ss[threadIdx.x] = s; ss2[threadIdx.x] = s2;
    __syncthreads();
    for (int o = 128; o; o >>= 1) {
        if (threadIdx.x < o) { ss[threadIdx.x] += ss[threadIdx.x + o]; ss2[threadIdx.x] += ss2[threadIdx.x + o]; }
        __syncthreads();
    }
    if (threadIdx.x == 0) {
        float m = ss[0] / 25600.f;
        float v = ss2[0] / 25600.f - m * m;
        stats[blockIdx.x * 2] = m;
        stats[blockIdx.x * 2 + 1] = v;
    }
}

__global__ void gn_apply_kernel(float* __restrict__ buf, const float* __restrict__ stats,
                                const float* __restrict__ g, const float* __restrict__ bb) {
    int idx = blockIdx.x * blockDim.x + threadIdx.x;
    if (idx >= 8 * 102400) return;
    int c = (idx / 12800) & 7;
    int b = idx / 102400;
    int grp = c >> 1;
    float m = stats[(b * 4 + grp) * 2];
    float v = stats[(b * 4 + grp) * 2 + 1];
    float val = (buf[idx] - m) * rsqrtf(v + 1e-5f) * g[c] + bb[c];
    buf[idx] = gelu_exact(val);
}

// ---------------- embed ----------------
__global__ void embed_kernel(const float* __restrict__ conv, const float* __restrict__ cls,
                             const float* __restrict__ pos, const float* __restrict__ te,
                             float* __restrict__ h) {
    int idx = blockIdx.x * blockDim.x + threadIdx.x;
    if (idx >= 8 * 513 * 200) return;
    int d = idx % 200;
    int n = (idx / 200) % 513;
    int b = idx / (200 * 513);
    float val;
    if (n == 0) {
        val = cls[d] + pos[d];
    } else {
        int p = n - 1;
        int t = d >> 3;
        int c = d & 7;
        val = conv[b * 102400 + c * 12800 + p * 25 + t];
        int ch = p >> 3, tw = p & 7;
        val += pos[(1 + ch) * 200 + d] + te[tw * 200 + d];
    }
    h[idx] = val;
}

// ---------------- weight convert+pad: fp32 [R][K] -> bf16 [R][KP] ----------------
__global__ void convpad_kernel(const float* __restrict__ src, short* __restrict__ dst,
                               int R, int K, int KP) {
    int idx = blockIdx.x * blockDim.x + threadIdx.x;
    if (idx >= R * KP) return;
    int r = idx / KP, c = idx % KP;
    dst[idx] = (c < K) ? f2bf(src[r * K + c]) : (short)0;
}

// ---------------- bias precompute: bias[h][q][576] bf16 (k pad -> 0) ----------------
__global__ void bias_pre_kernel(const float* __restrict__ table, const int* __restrict__ ridx,
                                short* __restrict__ bias) {
    int idx = blockIdx.x * blockDim.x + threadIdx.x;
    if (idx >= 10 * 513 * 144) return;
    int j = idx % 144;
    int q = (idx / 144) % 513;
    int h = idx / (144 * 513);
    int k0 = j * 4;
    const int* rp = ridx + q * 513;
    float v[4];
#pragma unroll
    for (int e = 0; e < 4; e++) {
        int k = k0 + e;
        v[e] = (k < 513) ? table[rp[k] * 10 + h] : 0.f;
    }
    uint2 pk;
    pk.x = pack2bf(v[0], v[1]);
    pk.y = pack2bf(v[2], v[3]);
    *(uint2*)&bias[((size_t)h * 513 + q) * 576 + k0] = pk;
}

// ---------------- LayerNorm over D=200, one wave per row; bf16 [row][256] out ----------------
__global__ __launch_bounds__(64) void ln_kernel(const float* __restrict__ in,
                                                const float* __restrict__ g,
                                                const float* __restrict__ b,
                                                short* __restrict__ out) {
    int row = blockIdx.x;
    int lane = threadIdx.x;
    const float* x = in + row * 200;
    float v[4];
    float s = 0.f;
#pragma unroll
    for (int i = 0; i < 4; i++) {
        int d = lane + i * 64;
        v[i] = (d < 200) ? x[d] : 0.f;
        s += v[i];
    }
#pragma unroll
    for (int o = 32; o; o >>= 1) s += __shfl_xor(s, o);
    float mean = s * (1.f / 200.f);
    float s2 = 0.f;
#pragma unroll
    for (int i = 0; i < 4; i++) {
        int d = lane + i * 64;
        float dv = (d < 200) ? (v[i] - mean) : 0.f;
        s2 += dv * dv;
    }
#pragma unroll
    for (int o = 32; o; o >>= 1) s2 += __shfl_xor(s2, o);
    float rstd = rsqrtf(s2 * (1.f / 200.f) + 1e-6f);
#pragma unroll
    for (int i = 0; i < 4; i++) {
        int d = lane + i * 64;
        float val = (d < 200) ? (v[i] - mean) * rstd * g[d] + b[d] : 0.f;
        out[row * 256 + d] = f2bf(val);
    }
}

// ---------------- bf16 MFMA GEMM: C[M,N] = A[M,KP] @ W[N,KP]^T (+ epilogue) ----------------
// BM x BN block tile (BM,BN in {64,128}), BK=64, 4 waves 2x2, wave tile (BM/2)x(BN/2).
// EPI 0: Cf = acc (fp32)
// EPI 1: Cf = res + gamma[n]*(acc+bias[n])
// EPI 2: Cb = bf16(gelu(acc+bias[n])), zero pad cols N..NPout
// EPI 3: qkv scatter -> Qb[b][h][576][32] (scaled), Kb same, Vt[b][h][32][576]
template <int EPI, int BM, int BN>
__global__ __launch_bounds__(256) void gemm_bf(const short* __restrict__ A,
                                               const short* __restrict__ W,
                                               float* __restrict__ Cf,
                                               short* __restrict__ Cb,
                                               const float* __restrict__ res,
                                               const float* __restrict__ bias,
                                               const float* __restrict__ gamma,
                                               int M, int N, int KP, int ldc, int NPout,
                                               short* __restrict__ Qb = nullptr,
                                               short* __restrict__ Kb = nullptr,
                                               short* __restrict__ Vt = nullptr) {
    constexpr int WM = BM / 2, WN = BN / 2;
    constexpr int AM = WM / 16, BNr = WN / 16;
    __shared__ __align__(16) short Ss[(BM + BN) * 64];

    const int tid = threadIdx.x;
    const int w = tid >> 6, l = tid & 63;
    const int wm = (w >> 1) * WM, wn = (w & 1) * WN;
    const int bm = blockIdx.y * BM, bn = blockIdx.x * BN;

    f32x4 acc[AM][BNr] = {};

    for (int k0 = 0; k0 < KP; k0 += 64) {
        __syncthreads();
#pragma unroll
        for (int it = 0; it < (BM + BN) / 32; it++) {
            int lin = it * 256 + tid;
            int row = lin >> 3, slot = lin & 7;
            int srcslot = slot ^ (row & 7);
            const short* g;
            if (it * 32 < BM) {
                g = A + (size_t)(bm + row) * KP + k0 + srcslot * 8;
            } else {
                g = W + (size_t)(bn + row - BM) * KP + k0 + srcslot * 8;
            }
            gload_lds16(g, (char*)Ss + lin * 16);
        }
        __syncthreads();

#pragma unroll
        for (int kk = 0; kk < 2; kk++) {
            const int kbyte = kk * 64 + (l >> 4) * 16;
            bf16x8 af[AM], bfr[BNr];
#pragma unroll
            for (int i = 0; i < AM; i++) {
                int r = wm + i * 16 + (l & 15);
                af[i] = *(const bf16x8*)((const char*)Ss + r * 128 + (kbyte ^ ((r & 7) << 4)));
            }
#pragma unroll
            for (int j = 0; j < BNr; j++) {
                int r = BM + wn + j * 16 + (l & 15);
                bfr[j] = *(const bf16x8*)((const char*)Ss + r * 128 + (kbyte ^ ((r & 7) << 4)));
            }
#pragma unroll
            for (int i = 0; i < AM; i++)
#pragma unroll
                for (int j = 0; j < BNr; j++)
                    acc[i][j] = __builtin_amdgcn_mfma_f32_16x16x32_bf16(af[i], bfr[j], acc[i][j], 0, 0, 0);
        }
    }

    const int col0 = bn + wn + (l & 15);
    const int rbase = (l >> 4) * 4;
#pragma unroll
    for (int i = 0; i < AM; i++) {
#pragma unroll
        for (int r = 0; r < 4; r++) {
            int gm = bm + wm + i * 16 + rbase + r;
            if (gm >= M) continue;
#pragma unroll
            for (int j = 0; j < BNr; j++) {
                int gn = col0 + j * 16;
                float v = acc[i][j][r];
                if (EPI == 0) {
                    if (gn < N) Cf[(size_t)gm * ldc + gn] = v;
                } else if (EPI == 1) {
                    if (gn < N) Cf[(size_t)gm * ldc + gn] =
                        res[(size_t)gm * ldc + gn] + gamma[gn] * (v + bias[gn]);
                } else if (EPI == 2) {
                    if (gn < NPout)
                        Cb[(size_t)gm * ldc + gn] = (gn < N) ? f2bf(gelu_exact(v + bias[gn])) : (short)0;
                } else {  // EPI 3: qkv scatter
                    if (gn < 600) {
                        int bb2 = gm / 513, n = gm - bb2 * 513;
                        if (gn < 200) {
                            int hq = gn / 20, dq = gn - hq * 20;
                            Qb[((size_t)(bb2 * 10 + hq) * 576 + n) * 32 + dq] =
                                f2bf(v * 0.22360679774997896f);
                        } else if (gn < 400) {
                            int gk = gn - 200, hk = gk / 20, dk = gk - hk * 20;
                            Kb[((size_t)(bb2 * 10 + hk) * 576 + n) * 32 + dk] = f2bf(v);
                        } else {
                            int gv = gn - 400, hv = gv / 20, dv2 = gv - hv * 20;
                            Vt[((size_t)(bb2 * 10 + hv) * 32 + dv2) * 576 + n] = f2bf(v);
                        }
                    }
                }
            }
        }
    }
}

// ---------------- MFMA flash attention v2: gload_lds staging from pre-layout buffers -----
// 720 blocks (XCD-chunked), 256 thr = 4 waves x 16 queries. All LDS XOR-chunk-swizzled.
__global__ __launch_bounds__(256) void attn_mfma2(const short* __restrict__ Qb,
                                                  const short* __restrict__ Kb,
                                                  const short* __restrict__ Vt,
                                                  const short* __restrict__ biasb,
                                                  short* __restrict__ ob) {
    __shared__ __align__(16) short Klds[64 * 32];   // [key][32d], chunk swz ^((row>>2)&3)
    __shared__ __align__(16) short Vlds[32 * 64];   // [d][64k], chunk swz ^(row&7)
    __shared__ __align__(16) short Blds[64 * 64];   // [q][64k], chunk swz ^(row&7)
    __shared__ __align__(16) short Pl[4 * 16 * 72]; // per-wave [q][72]

    const int orig = blockIdx.x;
    const int wg = (orig & 7) * 90 + (orig >> 3);   // XCD-chunked bijection (720 = 8*90)
    const int hh = wg / 72;
    const int rem = wg % 72;
    const int qt = rem >> 3, b = rem & 7;

    const int t = threadIdx.x, wave = t >> 6, l = t & 63;
    const int lq = l & 15, hi = l >> 4;
    const int n = qt * 64 + wave * 16 + lq;
    const int nc = min(n, 512);

    const size_t bh = (size_t)(b * 10 + hh);
    const short* Kbase = Kb + bh * 576 * 32;
    const short* Vbase = Vt + bh * 32 * 576;
    const short* Bbase = biasb + (size_t)hh * 513 * 576;

    // Q fragment (pre-scaled, zero-padded d>=20)
    bf16x8 qf = *(const bf16x8*)&Qb[(bh * 576 + nc) * 32 + hi * 8];

    // staging addresses (hoisted)
    const int krow = t >> 2, kch = t & 3;
    const short* ksrc = Kbase + (size_t)krow * 32 + (kch ^ ((krow >> 2) & 3)) * 8;
    const int vrow = t >> 3, vch = t & 7;
    const short* vsrc = Vbase + (size_t)vrow * 576 + (vch ^ (vrow & 7)) * 8;
    const int b0row = t >> 3, b0ch = t & 7;
    const short* bsrc0 = Bbase + (size_t)min(qt * 64 + b0row, 512) * 576 + (b0ch ^ (b0row & 7)) * 8;
    const int b1row = 32 + (t >> 3);
    const short* bsrc1 = Bbase + (size_t)min(qt * 64 + b1row, 512) * 576 + (b0ch ^ (b1row & 7)) * 8;

    float mrun = -1e30f, lsum = 0.f;
    f32x4 oacc0 = {}, oacc1 = {};
    const f32x4 zero4 = {};

    for (int kt = 0; kt < 9; kt++) {
        __syncthreads();
        const int koff = kt * 64;
        gload_lds16(ksrc + (size_t)koff * 32, (char*)Klds + t * 16);
        gload_lds16(vsrc + koff, (char*)Vlds + t * 16);
        gload_lds16(bsrc0 + koff, (char*)Blds + t * 16);
        gload_lds16(bsrc1 + koff, (char*)Blds + 4096 + t * 16);
        __syncthreads();

        // S^T: 4 mfma over 16-key chunks
        f32x4 s[4];
#pragma unroll
        for (int c = 0; c < 4; c++) {
            int r = c * 16 + lq;
            bf16x8 kf = *(const bf16x8*)((const char*)Klds + r * 64 + ((hi ^ ((lq >> 2) & 3)) << 4));
            s[c] = __builtin_amdgcn_mfma_f32_16x16x32_bf16(kf, qf, zero4, 0, 0, 0);
        }

        // bias add (from swizzled LDS) + key mask + row stats
        const int brow = wave * 16 + lq;
        float sv[4][4];
        float tm = -1e30f;
#pragma unroll
        for (int c = 0; c < 4; c++) {
            uint2 bl = *(const uint2*)((const char*)Blds + brow * 128 +
                                       (((2 * c + (hi >> 1)) ^ (lq & 7)) << 4) + (hi & 1) * 8);
            float bv[4] = { bf2f((unsigned short)(bl.x & 0xFFFF)), bf2f((unsigned short)(bl.x >> 16)),
                            bf2f((unsigned short)(bl.y & 0xFFFF)), bf2f((unsigned short)(bl.y >> 16)) };
            int kglob = koff + c * 16 + hi * 4;
#pragma unroll
            for (int r = 0; r < 4; r++) {
                float val = s[c][r] + bv[r];
                if (kglob + r > 512) val = -1e30f;
                sv[c][r] = val;
                tm = fmaxf(tm, val);
            }
        }
        tm = fmaxf(tm, __shfl_xor(tm, 16));
        tm = fmaxf(tm, __shfl_xor(tm, 32));
        float mnew = fmaxf(mrun, tm);
        float resc = __expf(mrun - mnew);
        mrun = mnew;

        float ts = 0.f;
#pragma unroll
        for (int c = 0; c < 4; c++) {
            float p0 = __expf(sv[c][0] - mnew);
            float p1 = __expf(sv[c][1] - mnew);
            float p2 = __expf(sv[c][2] - mnew);
            float p3 = __expf(sv[c][3] - mnew);
            ts += (p0 + p1) + (p2 + p3);
            uint2 pk;
            pk.x = pack2bf(p0, p1);
            pk.y = pack2bf(p2, p3);
            *(uint2*)&Pl[wave * 1152 + lq * 72 + c * 16 + hi * 4] = pk;
        }
        ts += __shfl_xor(ts, 16);
        ts += __shfl_xor(ts, 32);
        lsum = lsum * resc + ts;
        oacc0 *= resc;
        oacc1 *= resc;

        // PV: O^T += V^T . P^T
#pragma unroll
        for (int kc = 0; kc < 2; kc++) {
            bf16x8 pf = *(const bf16x8*)&Pl[wave * 1152 + lq * 72 + kc * 32 + hi * 8];
            bf16x8 vf0 = *(const bf16x8*)((const char*)Vlds + lq * 128 +
                                          (((kc * 4 + hi) ^ (lq & 7)) << 4));
            bf16x8 vf1 = *(const bf16x8*)((const char*)Vlds + (16 + lq) * 128 +
                                          (((kc * 4 + hi) ^ (lq & 7)) << 4));
            oacc0 = __builtin_amdgcn_mfma_f32_16x16x32_bf16(vf0, pf, oacc0, 0, 0, 0);
            oacc1 = __builtin_amdgcn_mfma_f32_16x16x32_bf16(vf1, pf, oacc1, 0, 0, 0);
        }
    }

    if (n < 513) {
        float inv = 1.f / lsum;
        short* op = ob + (size_t)(b * 513 + n) * 256 + hh * 20;
        {
            uint2 pk;
            pk.x = pack2bf(oacc0[0] * inv, oacc0[1] * inv);
            pk.y = pack2bf(oacc0[2] * inv, oacc0[3] * inv);
            *(uint2*)&op[hi * 4] = pk;
        }
        if (hi == 0) {
            uint2 pk;
            pk.x = pack2bf(oacc1[0] * inv, oacc1[1] * inv);
            pk.y = pack2bf(oacc1[2] * inv, oacc1[3] * inv);
            *(uint2*)&op[16] = pk;
        }
    }
}

// ---------------- final: mean-pool patches -> LN -> head (200 -> 4) ----------------
__global__ __launch_bounds__(256) void final_kernel(const float* __restrict__ h,
                                                    const float* __restrict__ g,
                                                    const float* __restrict__ bb,
                                                    const float* __restrict__ hw,
                                                    const float* __restrict__ hb,
                                                    float* __restrict__ out) {
    __shared__ float pool[256];
    __shared__ float red[256];
    int b = blockIdx.x, t = threadIdx.x;
    float s = 0.f;
    if (t < 200) {
        const float* hp = h + b * 513 * 200 + 200 + t;
        for (int p = 0; p < 512; p++) s += hp[p * 200];
        s *= (1.f / 512.f);
    }
    pool[t] = (t < 200) ? s : 0.f;
    red[t] = pool[t];
    __syncthreads();
    for (int o = 128; o; o >>= 1) {
        if (t < o) red[t] += red[t + o];
        __syncthreads();
    }
    float mean = red[0] / 200.f;
    __syncthreads();
    float dv = (t < 200) ? (pool[t] - mean) : 0.f;
    red[t] = dv * dv;
    __syncthreads();
    for (int o = 128; o; o >>= 1) {
        if (t < o) red[t] += red[t + o];
        __syncthreads();
    }
    float var = red[0] / 200.f;
    float rstd = rsqrtf(var + 1e-6f);
    __syncthreads();
    if (t < 200) pool[t] = (pool[t] - mean) * rstd * g[t] + bb[t];
    __syncthreads();
    if (t < 4) {
        float acc = hb[t];
        for (int d2 = 0; d2 < 200; d2++) acc += pool[d2] * hw[t * 200 + d2];
        out[b * 4 + t] = acc;
    }
}

extern "C" void kernel_launch(void* const* d_in, const int* in_sizes, int n_in,
                              void* d_out, int out_size, void* d_ws, size_t ws_size,
                              hipStream_t stream) {
    const float* x        = (const float*)d_in[0];
    const float* conv1_w  = (const float*)d_in[1];
    const float* conv1_b  = (const float*)d_in[2];
    const float* gn1_g    = (const float*)d_in[3];
    const float* gn1_b    = (const float*)d_in[4];
    const float* conv2_w  = (const float*)d_in[5];
    const float* conv2_b  = (const float*)d_in[6];
    const float* gn2_g    = (const float*)d_in[7];
    const float* gn2_b    = (const float*)d_in[8];
    const float* conv3_w  = (const float*)d_in[9];
    const float* conv3_b  = (const float*)d_in[10];
    const float* gn3_g    = (const float*)d_in[11];
    const float* gn3_b    = (const float*)d_in[12];
    const float* cls_tok  = (const float*)d_in[13];
    const float* pos_emb  = (const float*)d_in[14];
    const float* time_emb = (const float*)d_in[15];
    const float* ln1_g    = (const float*)d_in[16];
    const float* ln1_b    = (const float*)d_in[17];
    const float* qkv_w    = (const float*)d_in[18];
    const float* rel_tab  = (const float*)d_in[19];
    const float* proj_w   = (const float*)d_in[20];
    const float* proj_b   = (const float*)d_in[21];
    const float* gamma1   = (const float*)d_in[22];
    const float* ln2_g    = (const float*)d_in[23];
    const float* ln2_b    = (const float*)d_in[24];
    const float* fc1_w    = (const float*)d_in[25];
    const float* fc1_b    = (const float*)d_in[26];
    const float* fc2_w    = (const float*)d_in[27];
    const float* fc2_b    = (const float*)d_in[28];
    const float* gamma2   = (const float*)d_in[29];
    const float* fcn_g    = (const float*)d_in[30];
    const float* fcn_b    = (const float*)d_in[31];
    const float* head_w   = (const float*)d_in[32];
    const float* head_b   = (const float*)d_in[33];
    const int*   rel_idx  = (const int*)d_in[34];

    // ---- workspace layout (bytes), total ~37.1 MB ----
    char* p = (char*)d_ws;
    float* h    = (float*)p; p += 3283200;          // 8*513*200 f32
    // multi-phase region (9,849,600 B): conv scratch -> QKV bufs -> mlp
    char* qreg = p;
    float* c1   = (float*)qreg;
    float* c2   = c1 + 819200;
    short* Qb   = (short*)qreg;                     // [8][10][576][32] = 1,474,560 shorts
    short* Kb   = Qb + 1474560;
    short* Vt   = Kb + 1474560;                     // [8][10][32][576]
    short* mlp  = (short*)qreg;                     // [4104][832] (MLP phase)
    p += 9849600;
    short* y    = (short*)p; p += 2101248;          // 4104*256 bf16
    short* ob   = (short*)p; p += 2101248;          // 4104*256 bf16
    short* wqkv = (short*)p; p += 3686400;          // 12*600*256
    short* wproj= (short*)p; p += 1228800;          // 12*200*256
    short* wfc1 = (short*)p; p += 4915200;          // 12*800*256
    short* wfc2 = (short*)p; p += 3993600;          // 12*200*832
    short* biasb= (short*)p; p += 5909760;          // 10*513*576
    float* stats= (float*)p;                        // 256 B

    // ---- weight convert+pad ----
    convpad_kernel<<<(7200 * 256 + 255) / 256, 256, 0, stream>>>(qkv_w, wqkv, 7200, 200, 256);
    convpad_kernel<<<(2400 * 256 + 255) / 256, 256, 0, stream>>>(proj_w, wproj, 2400, 200, 256);
    convpad_kernel<<<(9600 * 256 + 255) / 256, 256, 0, stream>>>(fc1_w, wfc1, 9600, 200, 256);
    convpad_kernel<<<(2400 * 832 + 255) / 256, 256, 0, stream>>>(fc2_w, wfc2, 2400, 800, 832);
    hipMemsetAsync(ob, 0, 2101248, stream);

    // ---- patch embed ----
    conv1_kernel<<<3200, 256, 0, stream>>>(x, conv1_w, conv1_b, c1);
    gn_stats_kernel<<<32, 256, 0, stream>>>(c1, stats);
    gn_apply_kernel<<<3200, 256, 0, stream>>>(c1, stats, gn1_g, gn1_b);
    conv3x1_kernel<<<3200, 256, 0, stream>>>(c1, conv2_w, conv2_b, c2);
    gn_stats_kernel<<<32, 256, 0, stream>>>(c2, stats);
    gn_apply_kernel<<<3200, 256, 0, stream>>>(c2, stats, gn2_g, gn2_b);
    conv3x1_kernel<<<3200, 256, 0, stream>>>(c2, conv3_w, conv3_b, c1);
    gn_stats_kernel<<<32, 256, 0, stream>>>(c1, stats);
    gn_apply_kernel<<<3200, 256, 0, stream>>>(c1, stats, gn3_g, gn3_b);
    embed_kernel<<<(820800 + 255) / 256, 256, 0, stream>>>(c1, cls_tok, pos_emb, time_emb, h);

    // zero QKV pad regions (after conv phase - same memory)
    hipMemsetAsync(Qb, 0, 3 * 1474560 * 2, stream);

    // ---- transformer layers ----
    for (int d = 0; d < 12; d++) {
        ln_kernel<<<4104, 64, 0, stream>>>(h, ln1_g + d * 200, ln1_b + d * 200, y);
        gemm_bf<3, 64, 128><<<dim3(5, 65), 256, 0, stream>>>(y, wqkv + d * 153600,
                                                             nullptr, nullptr, nullptr, nullptr, nullptr,
                                                             4104, 600, 256, 0, 0, Qb, Kb, Vt);
        bias_pre_kernel<<<(10 * 513 * 144 + 255) / 256, 256, 0, stream>>>(rel_tab + d * 19080, rel_idx, biasb);
        attn_mfma2<<<720, 256, 0, stream>>>(Qb, Kb, Vt, biasb, ob);
        gemm_bf<1, 64, 64><<<dim3(4, 65), 256, 0, stream>>>(ob, wproj + d * 51200, h, nullptr,
                                                            h, proj_b + d * 200, gamma1 + d * 200,
                                                            4104, 200, 256, 200, 0);
        ln_kernel<<<4104, 64, 0, stream>>>(h, ln2_g + d * 200, ln2_b + d * 200, y);
        gemm_bf<2, 64, 128><<<dim3(7, 65), 256, 0, stream>>>(y, wfc1 + d * 204800, nullptr, mlp,
                                                             nullptr, fc1_b + d * 800, nullptr,
                                                             4104, 800, 256, 832, 832);
        gemm_bf<1, 64, 64><<<dim3(4, 65), 256, 0, stream>>>(mlp, wfc2 + d * 166400, h, nullptr,
                                                            h, fc2_b + d * 200, gamma2 + d * 200,
                                                            4104, 200, 832, 200, 0);
    }

    // ---- pool + head ----
    final_kernel<<<8, 256, 0, stream>>>(h, fcn_g, fcn_b, head_w, head_b, (float*)d_out);
}